// Round 2
// baseline (10419.391 us; speedup 1.0000x reference)
//
#include <hip/hip_runtime.h>

// ============================================================================
// TransformerNLI forward on MI355X (gfx950).
// bf16 MFMA GEMMs with LayerNorm folded into projection weights.
// Workspace budget: 264,318,976 bytes (guarded).
// ============================================================================

using u16 = unsigned short;
using u32 = unsigned int;

typedef __bf16 bf16x8 __attribute__((ext_vector_type(8)));
typedef u16    u16x8  __attribute__((ext_vector_type(8)));
typedef float  f32x4  __attribute__((ext_vector_type(4)));

#define D_THRESH 3.8918203f   // log(2000/40 - 1)

__device__ __forceinline__ u16 f2bf(float f) {
    u32 u = __builtin_bit_cast(u32, f);
    u32 r = (u + 0x7fffu + ((u >> 16) & 1u)) >> 16;   // RNE
    return (u16)r;
}
__device__ __forceinline__ float bf2f(u16 h) {
    u32 u = ((u32)h) << 16;
    return __builtin_bit_cast(float, u);
}
__device__ __forceinline__ bf16x8 ld_bf8(const u16* p) {
    u16x8 v = *(const u16x8*)p;
    return __builtin_bit_cast(bf16x8, v);
}

// global -> LDS async copy, 16B per lane; LDS dest = wave-uniform base + lane*16
#define GLD_LDS(gptr, lptr)                                                     \
    __builtin_amdgcn_global_load_lds(                                           \
        (const __attribute__((address_space(1))) u32*)(gptr),                   \
        (__attribute__((address_space(3))) u32*)(lptr), 16, 0, 0)

// ---------------------------------------------------------------------------
// Weight prep: fp32 [K,N] -> bf16 [N,K], optional per-k gamma scale, batched z
// ---------------------------------------------------------------------------
__global__ __launch_bounds__(256) void transpose_to_bf16(
    const float* __restrict__ in, u16* __restrict__ out,
    const float* __restrict__ gamma, int K, int N)
{
    __shared__ float tile[32][33];
    const float* src = in  + (size_t)blockIdx.z * K * N;
    u16*         dst = out + (size_t)blockIdx.z * K * N;
    const float* gm  = gamma ? gamma + (size_t)blockIdx.z * K : nullptr;
    int n0 = blockIdx.x * 32, k0 = blockIdx.y * 32;
#pragma unroll
    for (int i = 0; i < 4; ++i) {
        int k = k0 + threadIdx.y + i * 8;
        tile[threadIdx.y + i * 8][threadIdx.x] = src[(size_t)k * N + n0 + threadIdx.x];
    }
    __syncthreads();
#pragma unroll
    for (int i = 0; i < 4; ++i) {
        int n = n0 + threadIdx.y + i * 8;
        int kk = k0 + threadIdx.x;
        float v = tile[threadIdx.x][threadIdx.y + i * 8];
        if (gm) v *= gm[kk];
        dst[(size_t)n * K + kk] = f2bf(v);
    }
}

// u[n] = sum_k gamma[k]*W[k,n] ; d[n] = sum_k beta[k]*W[k,n] + bias[n]
__global__ __launch_bounds__(256) void colsum_ud(
    const float* __restrict__ W, const float* __restrict__ gamma,
    const float* __restrict__ beta, const float* __restrict__ bias,
    float* __restrict__ u, float* __restrict__ d, int K, int N)
{
    int n = blockIdx.x * 256 + threadIdx.x;
    const float* Wz = W + (size_t)blockIdx.z * K * N;
    const float* gz = gamma + (size_t)blockIdx.z * K;
    const float* bz = beta  + (size_t)blockIdx.z * K;
    float su = 0.f, sd = 0.f;
    for (int k = 0; k < K; ++k) {
        float w = Wz[(size_t)k * N + n];
        su += gz[k] * w;
        sd += bz[k] * w;
    }
    u[(size_t)blockIdx.z * N + n] = su;
    d[(size_t)blockIdx.z * N + n] = sd + bias[(size_t)blockIdx.z * N + n];
}

// per-row (mean, rstd) of bf16 [M,512]
__global__ __launch_bounds__(256) void row_stats(
    const u16* __restrict__ x, float2* __restrict__ st)
{
    const int lane = threadIdx.x & 63, w = threadIdx.x >> 6;
    const size_t row = (size_t)blockIdx.x * 4 + w;
    union { uint4 v; u16 h[8]; } a;
    a.v = *(const uint4*)(x + row * 512 + lane * 8);
    float s = 0.f, sq = 0.f;
#pragma unroll
    for (int j = 0; j < 8; ++j) { float f = bf2f(a.h[j]); s += f; sq += f * f; }
#pragma unroll
    for (int off = 1; off < 64; off <<= 1) {
        s  += __shfl_xor(s,  off, 64);
        sq += __shfl_xor(sq, off, 64);
    }
    if (lane == 0) {
        float m  = s * (1.f / 512.f);
        float vr = sq * (1.f / 512.f) - m * m;
        st[row] = make_float2(m, rsqrtf(vr + 1e-5f));
    }
}

// ---------------------------------------------------------------------------
// GEMM: C[M,N] = epi(A[M,K](bf16,lda) @ BT[N,K](bf16,ldb)^T)
// EPI: 0 bf16=acc+b | 1 bf16=relu(acc+b) | 2 bf16 C+=acc+b | 3 f32=acc(+b)
//      4 bf16=relu(resf+acc+b) | 5 bf16=rs*acc-rs*m*u[n]+d[n] | 6 relu(5)
//      7 bf16 C+=acc
// ---------------------------------------------------------------------------
template<int EPI>
__global__ __launch_bounds__(256) void gemm_bt(
    const u16* __restrict__ A, int lda,
    const u16* __restrict__ BT, int ldb,
    const float* __restrict__ bias,      // EPI5/6: the d[] vector
    const float* __restrict__ u,
    const float2* __restrict__ st,
    void* __restrict__ Cv, int ldc,
    const float* __restrict__ resf,
    int M, int N, int K)
{
    __shared__ u16 As[128 * 32];
    __shared__ u16 Bs[128 * 32];
    const int tid  = threadIdx.x;
    const int lane = tid & 63;
    const int w    = tid >> 6;
    const int wm   = w >> 1, wn = w & 1;
    const int m0   = blockIdx.y * 128, n0 = blockIdx.x * 128;
    const int g    = lane & 15, q = lane >> 4;

    const f32x4 fz = {0.f, 0.f, 0.f, 0.f};
    f32x4 acc[4][4];
#pragma unroll
    for (int i = 0; i < 4; ++i)
#pragma unroll
        for (int j = 0; j < 4; ++j) acc[i][j] = fz;

    for (int kt = 0; kt < K; kt += 32) {
#pragma unroll
        for (int i = 0; i < 2; ++i) {
            int c = (w * 2 + i) * 64 + lane;
            int r = c >> 2, cq = c & 3;
            GLD_LDS(A  + (size_t)(m0 + r) * lda + kt + cq * 8, As + (size_t)(w * 2 + i) * 512);
            GLD_LDS(BT + (size_t)(n0 + r) * ldb + kt + cq * 8, Bs + (size_t)(w * 2 + i) * 512);
        }
        __syncthreads();
        bf16x8 af[4], bfr[4];
#pragma unroll
        for (int i = 0; i < 4; ++i) af[i]  = ld_bf8(As + (wm * 64 + i * 16 + g) * 32 + q * 8);
#pragma unroll
        for (int j = 0; j < 4; ++j) bfr[j] = ld_bf8(Bs + (wn * 64 + j * 16 + g) * 32 + q * 8);
#pragma unroll
        for (int i = 0; i < 4; ++i)
#pragma unroll
            for (int j = 0; j < 4; ++j)
                acc[i][j] = __builtin_amdgcn_mfma_f32_16x16x32_bf16(af[i], bfr[j], acc[i][j], 0, 0, 0);
        __syncthreads();
    }
    // epilogue: row = m0+wm*64+i*16+q*4+r, col = n0+wn*64+j*16+g
#pragma unroll
    for (int j = 0; j < 4; ++j) {
        int col  = n0 + wn * 64 + j * 16 + g;
        float bj = bias ? bias[col] : 0.f;
        float un = (EPI == 5 || EPI == 6) ? u[col] : 0.f;
#pragma unroll
        for (int i = 0; i < 4; ++i) {
            int rb = m0 + wm * 64 + i * 16 + q * 4;
#pragma unroll
            for (int r = 0; r < 4; ++r) {
                float v = acc[i][j][r];
                size_t idx = (size_t)(rb + r) * ldc + col;
                if (EPI == 5 || EPI == 6) {
                    float2 s2 = st[rb + r];
                    v = s2.y * v - s2.y * s2.x * un + bj;
                } else {
                    v += bj;
                }
                if (EPI == 1 || EPI == 6) v = fmaxf(v, 0.f);
                if (EPI == 4) v = fmaxf(resf[idx] + v, 0.f);
                if (EPI == 2 || EPI == 7) v += bf2f(((u16*)Cv)[idx]);
                if (EPI == 3) ((float*)Cv)[idx] = v;
                else          ((u16*)Cv)[idx]   = f2bf(v);
            }
        }
    }
}

// ---------------------------------------------------------------------------
// Thresholded attention. Token row = s*128+b. One block = (b, h, 64 q-rows).
// Q[lq], K/V[lkv] strided; ctx written to O[lo] (may equal Q: block-disjoint).
// p = (s >= smax - D) ? exp(s - smax) : 0 ; out = (P V)/sum p
// ---------------------------------------------------------------------------
__global__ __launch_bounds__(256) void attn_kernel(
    const u16* __restrict__ Q, int lq,
    const u16* __restrict__ Kp, const u16* __restrict__ Vp, int lkv,
    u16* __restrict__ O, int lo)
{
    __shared__ u16 smem[32768];          // 64 KB
    u16* Ks  = smem;                     // [256][64]
    u16* Qs  = smem + 16384;             // [64][64]
    u16* Ps  = smem;                     // [64][256]  (phase 2)
    u16* VTs = smem + 16384;             // [64][256]

    const int tid = threadIdx.x, lane = tid & 63, w = tid >> 6;
    const int g = lane & 15, qd = lane >> 4;
    const int q0 = blockIdx.x * 64;
    const int b = blockIdx.y >> 3, h = blockIdx.y & 7;

#pragma unroll
    for (int i = 0; i < 8; ++i) {
        int c = (w * 8 + i) * 64 + lane;
        int r = c >> 3, cq = c & 7;
        GLD_LDS(Kp + (size_t)(r * 128 + b) * lkv + h * 64 + cq * 8,
                Ks + (size_t)(w * 8 + i) * 512);
    }
#pragma unroll
    for (int i = 0; i < 2; ++i) {
        int c = (w * 2 + i) * 64 + lane;
        int r = c >> 3, cq = c & 7;
        GLD_LDS(Q + (size_t)((q0 + r) * 128 + b) * lq + h * 64 + cq * 8,
                Qs + (size_t)(w * 2 + i) * 512);
    }
    __syncthreads();

    const f32x4 fz = {0.f, 0.f, 0.f, 0.f};
    f32x4 s[16];
#pragma unroll
    for (int t = 0; t < 16; ++t) s[t] = fz;
#pragma unroll
    for (int ks = 0; ks < 2; ++ks) {
        bf16x8 aq = ld_bf8(Qs + (w * 16 + g) * 64 + ks * 32 + qd * 8);
#pragma unroll
        for (int t = 0; t < 16; ++t) {
            bf16x8 bk = ld_bf8(Ks + (t * 16 + g) * 64 + ks * 32 + qd * 8);
            s[t] = __builtin_amdgcn_mfma_f32_16x16x32_bf16(aq, bk, s[t], 0, 0, 0);
        }
    }
    __syncthreads();   // Ks/Qs now free

    union { uint4 v; u16 us[8]; } vch[8];
#pragma unroll
    for (int i = 0; i < 8; ++i) {
        int c = i * 256 + tid;
        int r = c >> 3, cq = c & 7;
        vch[i].v = *(const uint4*)(Vp + (size_t)(r * 128 + b) * lkv + h * 64 + cq * 8);
    }

    float mrow[4] = {-1e30f, -1e30f, -1e30f, -1e30f};
#pragma unroll
    for (int t = 0; t < 16; ++t)
#pragma unroll
        for (int r = 0; r < 4; ++r) mrow[r] = fmaxf(mrow[r], s[t][r]);
#pragma unroll
    for (int off = 1; off < 16; off <<= 1)
#pragma unroll
        for (int r = 0; r < 4; ++r) mrow[r] = fmaxf(mrow[r], __shfl_xor(mrow[r], off, 64));
#pragma unroll
    for (int r = 0; r < 4; ++r) mrow[r] *= 0.125f;

    float l[4] = {0.f, 0.f, 0.f, 0.f};
#pragma unroll
    for (int t = 0; t < 16; ++t)
#pragma unroll
        for (int r = 0; r < 4; ++r) {
            float sc = s[t][r] * 0.125f;
            float p  = (sc >= mrow[r] - D_THRESH) ? __expf(sc - mrow[r]) : 0.f;
            u16 pb = f2bf(p);
            l[r] += bf2f(pb);
            Ps[(w * 16 + qd * 4 + r) * 256 + t * 16 + g] = pb;
        }
#pragma unroll
    for (int off = 1; off < 16; off <<= 1)
#pragma unroll
        for (int r = 0; r < 4; ++r) l[r] += __shfl_xor(l[r], off, 64);

#pragma unroll
    for (int i = 0; i < 8; ++i) {
        int c = i * 256 + tid;
        int r = c >> 3, cq = c & 7;
#pragma unroll
        for (int j = 0; j < 8; ++j) VTs[(cq * 8 + j) * 256 + r] = vch[i].us[j];
    }
    __syncthreads();

    f32x4 o[4];
#pragma unroll
    for (int nt = 0; nt < 4; ++nt) o[nt] = fz;
#pragma unroll
    for (int ks = 0; ks < 8; ++ks) {
        bf16x8 ap = ld_bf8(Ps + (w * 16 + g) * 256 + ks * 32 + qd * 8);
#pragma unroll
        for (int nt = 0; nt < 4; ++nt) {
            bf16x8 bv = ld_bf8(VTs + (nt * 16 + g) * 256 + ks * 32 + qd * 8);
            o[nt] = __builtin_amdgcn_mfma_f32_16x16x32_bf16(ap, bv, o[nt], 0, 0, 0);
        }
    }
    float rl[4];
#pragma unroll
    for (int r = 0; r < 4; ++r) rl[r] = 1.f / l[r];
#pragma unroll
    for (int nt = 0; nt < 4; ++nt)
#pragma unroll
        for (int r = 0; r < 4; ++r) {
            int srow = q0 + w * 16 + qd * 4 + r;
            O[(size_t)(srow * 128 + b) * lo + h * 64 + nt * 16 + g] = f2bf(o[nt][r] * rl[r]);
        }
}

// ---------------------------------------------------------------------------
// elementwise / small kernels
// ---------------------------------------------------------------------------
__global__ __launch_bounds__(256) void build_pe(float* __restrict__ pe) {
    int idx = blockIdx.x * 256 + threadIdx.x;   // 256*512
    int e = idx & 511, s = idx >> 9;
    int j = e >> 1;
    float fr = __expf((float)(2 * j) * (-0.017988946f));   // -ln(10000)/512
    float ph = (float)s * fr;
    pe[idx] = (e & 1) ? cosf(ph) : sinf(ph);
}

__global__ __launch_bounds__(256) void add_pe_bf16(
    const float* __restrict__ in, const float* __restrict__ pe, u16* __restrict__ out)
{
    size_t idx = (size_t)blockIdx.x * 256 + threadIdx.x;   // 32768*512
    int e = (int)(idx & 511);
    int s = (int)(idx >> 16);
    out[idx] = f2bf(in[idx] + pe[(s << 9) | e]);
}

__global__ __launch_bounds__(256) void add_bf16(
    u16* __restrict__ x, const u16* __restrict__ dlt)
{
    size_t i8 = ((size_t)blockIdx.x * 256 + threadIdx.x) * 8;
    union { uint4 v; u16 h[8]; } a, b;
    a.v = *(const uint4*)(x + i8);
    b.v = *(const uint4*)(dlt + i8);
#pragma unroll
    for (int j = 0; j < 8; ++j) a.h[j] = f2bf(bf2f(a.h[j]) + bf2f(b.h[j]));
    *(uint4*)(x + i8) = a.v;
}

__global__ __launch_bounds__(128) void pool_sum(
    const float* __restrict__ t2, u16* __restrict__ pcat, int colofs)
{
    int b = blockIdx.x >> 2, ec = blockIdx.x & 3;
    int e = ec * 128 + threadIdx.x;
    float acc = 0.f;
    for (int s = 0; s < 256; ++s) acc += t2[(size_t)(s * 128 + b) * 512 + e];
    pcat[b * 1024 + colofs + e] = f2bf(acc * 0.0625f);     // / sqrt(256)
}

__global__ __launch_bounds__(64) void fc4_kernel(
    const u16* __restrict__ a, const float* __restrict__ w,
    const float* __restrict__ bias, float* __restrict__ out)
{
    int id = blockIdx.x * 64 + threadIdx.x;                // 384 = 128*3
    if (id >= 384) return;
    int b = id / 3, l = id % 3;
    float acc = bias[l];
    for (int k = 0; k < 512; ++k) acc += bf2f(a[b * 512 + k]) * w[k * 3 + l];
    out[id] = acc;
}

__global__ __launch_bounds__(64) void sentinel_kernel(float* __restrict__ out) {
    int i = blockIdx.x * 64 + threadIdx.x;
    if (i < 384) out[i] = -12345.0f;
}

// ===========================================================================
extern "C" void kernel_launch(void* const* d_in, const int* in_sizes, int n_in,
                              void* d_out, int out_size, void* d_ws, size_t ws_size,
                              hipStream_t stream) {
    (void)in_sizes; (void)n_in; (void)out_size;

    const float* x_1       = (const float*)d_in[0];
    const float* x_2       = (const float*)d_in[1];
    const float* enc_ln1_g = (const float*)d_in[2];
    const float* enc_ln1_b = (const float*)d_in[3];
    const float* enc_Wqkv  = (const float*)d_in[4];
    const float* enc_bqkv  = (const float*)d_in[5];
    const float* enc_Wo    = (const float*)d_in[6];
    const float* enc_bo    = (const float*)d_in[7];
    const float* enc_ln2_g = (const float*)d_in[8];
    const float* enc_ln2_b = (const float*)d_in[9];
    const float* enc_W1    = (const float*)d_in[10];
    const float* enc_b1    = (const float*)d_in[11];
    const float* enc_W2    = (const float*)d_in[12];
    const float* enc_b2    = (const float*)d_in[13];
    const float* isa_ln_g  = (const float*)d_in[14];
    const float* isa_ln_b  = (const float*)d_in[15];
    const float* isa_Wqkv  = (const float*)d_in[16];
    const float* isa_bqkv  = (const float*)d_in[17];
    const float* isa_Wo    = (const float*)d_in[18];
    const float* isa_bo    = (const float*)d_in[19];
    const float* iea_ln_g  = (const float*)d_in[20];
    const float* iea_ln_b  = (const float*)d_in[21];
    const float* iea_Wqkv  = (const float*)d_in[22];
    const float* iea_bqkv  = (const float*)d_in[23];
    const float* iea_Wo    = (const float*)d_in[24];
    const float* iea_bo    = (const float*)d_in[25];
    const float* iff_ln_g  = (const float*)d_in[26];
    const float* iff_ln_b  = (const float*)d_in[27];
    const float* int_W1    = (const float*)d_in[28];
    const float* int_b1    = (const float*)d_in[29];
    const float* int_W2    = (const float*)d_in[30];
    const float* int_b2    = (const float*)d_in[31];
    const float* fc1_w     = (const float*)d_in[32];
    const float* fc1_b     = (const float*)d_in[33];
    const float* fc2_w     = (const float*)d_in[34];
    const float* fc2_b     = (const float*)d_in[35];
    const float* fc3_w     = (const float*)d_in[36];
    const float* fc3_b     = (const float*)d_in[37];
    const float* fc4_w     = (const float*)d_in[38];
    const float* fc4_b     = (const float*)d_in[39];
    float* out = (float*)d_out;

    const size_t WS_NEED = 264318976;
    if (ws_size < WS_NEED) {                 // diagnostic: absmax ~12345 => ws too small
        sentinel_kernel<<<6, 64, 0, stream>>>(out);
        return;
    }

    char* ws = (char*)d_ws;
    // ---- persistent transposed weights (byte offsets) ----------------------
    u16* isaQKV = (u16*)(ws + 0);         // [3][1536][512]
    u16* isaWO  = (u16*)(ws + 4718592);   // [3][512][512]
    u16* ieaQKV = (u16*)(ws + 6291456);
    u16* ieaWO  = (u16*)(ws + 11010048);
    u16* intW1  = (u16*)(ws + 12582912);  // [3][2048][512]
    u16* intW2  = (u16*)(ws + 18874368);  // [3][512][2048]
    u16* fc1T   = (u16*)(ws + 25165824);  // [512][1024]
    u16* fc2T   = (u16*)(ws + 26214400);  // [512][512]
    u16* fc3T   = (u16*)(ws + 26738688);  // [512][1024]
    float* UD   = (float*)(ws + 27787264);
    float* enc_qkv_u = UD;                // [3][1536]
    float* enc_qkv_d = UD + 4608;
    float* enc_w1_u  = UD + 9216;         // [3][2048]
    float* enc_w1_d  = UD + 15360;
    float* isa_qkv_u = UD + 21504;
    float* isa_qkv_d = UD + 26112;
    float* iea_qkv_u = UD + 30720;
    float* iea_qkv_d = UD + 35328;
    float* int_w1_u  = UD + 39936;
    float* int_w1_d  = UD + 46080;
    float2* stats1 = (float2*)(ws + 27996160);   // [32768]
    float2* stats2 = (float2*)(ws + 28258304);
    float*  pe     = (float*)(ws + 28520448);    // [256,512]
    u16*    pcat   = (u16*)(ws + 29044736);      // [128,1024]
    u16*    fc3o   = (u16*)(ws + 29306880);      // [128,512]
    u16*    x1     = (u16*)(ws + 29437952);      // [32768,512] bf16 residual
    u16*    x2     = (u16*)(ws + 62992384);
    // EREG: during encoder holds enc transposed weights; afterwards e1/e2
    u16* encQKV = (u16*)(ws + 96546816);             // [3][1536][512]
    u16* encWO  = (u16*)(ws + 96546816 + 4718592);   // [3][512][512]
    u16* encW1  = (u16*)(ws + 96546816 + 6291456);   // [3][2048][512]
    u16* encW2  = (u16*)(ws + 96546816 + 12582912);  // [3][512][2048]
    u16* e1     = (u16*)(ws + 96546816);             // [32768,512]
    u16* e2     = (u16*)(ws + 96546816 + 33554432);
    // BIG scratch: 96 MB, phase-dependent
    u16*   qkv  = (u16*)(ws + 163655680);            // [32768,1536]
    u16*   B0   = (u16*)(ws + 163655680);            // [32768,512]
    u16*   B1   = (u16*)(ws + 163655680 + 33554432); // [32768,1024]
    u16*   fbuf = (u16*)(ws + 163655680);            // [32768,1024]
    u16*   dlt  = (u16*)(ws + 163655680 + 67108864); // [32768,512]
    float* accf = (float*)(ws + 163655680);          // [32768,512] fp32
    u16*   hcls = (u16*)(ws + 163655680 + 67108864); // [32768,512]

    // ---- weight prep -------------------------------------------------------
    auto TR = [&](const float* in, u16* o, const float* g, int K, int N, int L) {
        transpose_to_bf16<<<dim3(N / 32, K / 32, L), dim3(32, 8), 0, stream>>>(in, o, g, K, N);
    };
    TR(enc_Wqkv, encQKV, enc_ln1_g, 512, 1536, 3);
    TR(enc_Wo,   encWO,  nullptr,   512, 512,  3);
    TR(enc_W1,   encW1,  enc_ln2_g, 512, 2048, 3);
    TR(enc_W2,   encW2,  nullptr,   2048, 512, 3);
    TR(isa_Wqkv, isaQKV, isa_ln_g,  512, 1536, 3);
    TR(isa_Wo,   isaWO,  nullptr,   512, 512,  3);
    TR(iea_Wqkv, ieaQKV, iea_ln_g,  512, 1536, 3);
    TR(iea_Wo,   ieaWO,  nullptr,   512, 512,  3);
    TR(int_W1,   intW1,  iff_ln_g,  512, 2048, 3);
    TR(int_W2,   intW2,  nullptr,   2048, 512, 3);
    TR(fc1_w, fc1T, nullptr, 1024, 512, 1);
    TR(fc2_w, fc2T, nullptr, 512,  512, 1);
    TR(fc3_w, fc3T, nullptr, 1024, 512, 1);
    colsum_ud<<<dim3(6, 1, 3), 256, 0, stream>>>(enc_Wqkv, enc_ln1_g, enc_ln1_b, enc_bqkv, enc_qkv_u, enc_qkv_d, 512, 1536);
    colsum_ud<<<dim3(8, 1, 3), 256, 0, stream>>>(enc_W1,   enc_ln2_g, enc_ln2_b, enc_b1,   enc_w1_u,  enc_w1_d,  512, 2048);
    colsum_ud<<<dim3(6, 1, 3), 256, 0, stream>>>(isa_Wqkv, isa_ln_g,  isa_ln_b,  isa_bqkv, isa_qkv_u, isa_qkv_d, 512, 1536);
    colsum_ud<<<dim3(6, 1, 3), 256, 0, stream>>>(iea_Wqkv, iea_ln_g,  iea_ln_b,  iea_bqkv, iea_qkv_u, iea_qkv_d, 512, 1536);
    colsum_ud<<<dim3(8, 1, 3), 256, 0, stream>>>(int_W1,   iff_ln_g,  iff_ln_b,  int_b1,   int_w1_u,  int_w1_d,  512, 2048);

    build_pe<<<512, 256, 0, stream>>>(pe);
    add_pe_bf16<<<65536, 256, 0, stream>>>(x_1, pe, x1);
    add_pe_bf16<<<65536, 256, 0, stream>>>(x_2, pe, x2);

    // ---- launch helpers ----------------------------------------------------
    auto G = [&](int epi, const u16* A, int lda, const u16* BT, int ldb,
                 const float* bias, const float* uu, const float2* stt,
                 void* C, int ldc, const float* resf, int M, int N, int K) {
        dim3 grid(N / 128, M / 128);
        switch (epi) {
        case 0: gemm_bt<0><<<grid, 256, 0, stream>>>(A, lda, BT, ldb, bias, uu, stt, C, ldc, resf, M, N, K); break;
        case 1: gemm_bt<1><<<grid, 256, 0, stream>>>(A, lda, BT, ldb, bias, uu, stt, C, ldc, resf, M, N, K); break;
        case 2: gemm_bt<2><<<grid, 256, 0, stream>>>(A, lda, BT, ldb, bias, uu, stt, C, ldc, resf, M, N, K); break;
        case 3: gemm_bt<3><<<grid, 256, 0, stream>>>(A, lda, BT, ldb, bias, uu, stt, C, ldc, resf, M, N, K); break;
        case 4: gemm_bt<4><<<grid, 256, 0, stream>>>(A, lda, BT, ldb, bias, uu, stt, C, ldc, resf, M, N, K); break;
        case 5: gemm_bt<5><<<grid, 256, 0, stream>>>(A, lda, BT, ldb, bias, uu, stt, C, ldc, resf, M, N, K); break;
        case 6: gemm_bt<6><<<grid, 256, 0, stream>>>(A, lda, BT, ldb, bias, uu, stt, C, ldc, resf, M, N, K); break;
        case 7: gemm_bt<7><<<grid, 256, 0, stream>>>(A, lda, BT, ldb, bias, uu, stt, C, ldc, resf, M, N, K); break;
        }
    };
    auto STATS = [&](const u16* x, float2* stt) {
        row_stats<<<8192, 256, 0, stream>>>(x, stt);
    };
    auto ATT = [&](const u16* Qp, int lq, const u16* Kp, const u16* Vp, int lkv,
                   u16* Op, int lo) {
        attn_kernel<<<dim3(4, 1024), 256, 0, stream>>>(Qp, lq, Kp, Vp, lkv, Op, lo);
    };

    // self-attn + FFN block (encoder & interaction share the shape)
    auto self_block = [&](u16* x, u16* wqkvT, const float* qu, const float* qd,
                          u16* woT, const float* bo,
                          u16* w1T, const float* w1u, const float* w1d,
                          u16* w2T, const float* b2, bool do_ffn) {
        STATS(x, stats1);
        G(5, x, 512, wqkvT, 512, qd, qu, stats1, qkv, 1536, nullptr, 32768, 1536, 512);
        ATT(qkv, 1536, qkv + 512, qkv + 1024, 1536, qkv, 1536);
        G(2, qkv, 1536, woT, 512, bo, nullptr, nullptr, x, 512, nullptr, 32768, 512, 512);
        if (do_ffn) {
            STATS(x, stats1);
            G(6, x, 512, w1T, 512, w1d, w1u, stats1, fbuf, 1024, nullptr, 32768, 1024, 512);
            G(0, fbuf, 1024, w2T, 2048, b2, nullptr, nullptr, dlt, 512, nullptr, 32768, 512, 1024);
            G(6, x, 512, w1T + 1024 * 512, 512, w1d + 1024, w1u + 1024, stats1, fbuf, 1024, nullptr, 32768, 1024, 512);
            G(7, fbuf, 1024, w2T + 1024, 2048, nullptr, nullptr, nullptr, dlt, 512, nullptr, 32768, 512, 1024);
            add_bf16<<<8192, 256, 0, stream>>>(x, dlt);
        }
    };

    // ---- Siamese encoder ---------------------------------------------------
    for (int i = 0; i < 3; ++i)
        for (int st = 0; st < 2; ++st)
            self_block(st ? x2 : x1,
                       encQKV + (size_t)i * 786432, enc_qkv_u + i * 1536, enc_qkv_d + i * 1536,
                       encWO + (size_t)i * 262144, enc_bo + i * 512,
                       encW1 + (size_t)i * 1048576, enc_w1_u + i * 2048, enc_w1_d + i * 2048,
                       encW2 + (size_t)i * 1048576, enc_b2 + i * 512, true);

    // snapshots (enc weights in EREG are dead now)
    hipMemcpyAsync(e1, x1, 33554432, hipMemcpyDeviceToDevice, stream);
    hipMemcpyAsync(e2, x2, 33554432, hipMemcpyDeviceToDevice, stream);

    // ---- interaction stack -------------------------------------------------
    for (int i = 0; i < 3; ++i) {
        // self-attn (isa), no FFN inside
        for (int st = 0; st < 2; ++st)
            self_block(st ? x2 : x1,
                       isaQKV + (size_t)i * 786432, isa_qkv_u + i * 1536, isa_qkv_d + i * 1536,
                       isaWO + (size_t)i * 262144, isa_bo + i * 512,
                       nullptr, nullptr, nullptr, nullptr, nullptr, false);
        // cross-attn (iea): h1,h2 from pre-update x1,x2
        u16* qT  = ieaQKV + (size_t)i * 786432;
        u16* kvT = qT + 512 * 512;
        const float* qu = iea_qkv_u + i * 1536;
        const float* qd = iea_qkv_d + i * 1536;
        STATS(x2, stats2);
        G(5, x2, 512, kvT, 512, qd + 512, qu + 512, stats2, B1, 1024, nullptr, 32768, 1024, 512); // kv2
        STATS(x1, stats1);
        G(5, x1, 512, qT, 512, qd, qu, stats1, B0, 512, nullptr, 32768, 512, 512);               // q1
        ATT(B0, 512, B1, B1 + 512, 1024, B0, 512);                                               // ctx1
        G(5, x1, 512, kvT, 512, qd + 512, qu + 512, stats1, B1, 1024, nullptr, 32768, 1024, 512); // kv1 (x1 still old)
        G(2, B0, 512, ieaWO + (size_t)i * 262144, 512, iea_bo + i * 512, nullptr, nullptr,
          x1, 512, nullptr, 32768, 512, 512);                                                    // x1 += y1
        G(5, x2, 512, qT, 512, qd, qu, stats2, B0, 512, nullptr, 32768, 512, 512);               // q2 (x2 still old)
        ATT(B0, 512, B1, B1 + 512, 1024, B0, 512);                                               // ctx2
        G(2, B0, 512, ieaWO + (size_t)i * 262144, 512, iea_bo + i * 512, nullptr, nullptr,
          x2, 512, nullptr, 32768, 512, 512);                                                    // x2 += y2
        // FFN (int/iff)
        for (int st = 0; st < 2; ++st) {
            u16* x = st ? x2 : x1;
            STATS(x, stats1);
            u16* w1T = intW1 + (size_t)i * 1048576;
            u16* w2T = intW2 + (size_t)i * 1048576;
            const float* w1u = int_w1_u + i * 2048;
            const float* w1d = int_w1_d + i * 2048;
            G(6, x, 512, w1T, 512, w1d, w1u, stats1, fbuf, 1024, nullptr, 32768, 1024, 512);
            G(0, fbuf, 1024, w2T, 2048, int_b2 + i * 512, nullptr, nullptr, dlt, 512, nullptr, 32768, 512, 1024);
            G(6, x, 512, w1T + 1024 * 512, 512, w1d + 1024, w1u + 1024, stats1, fbuf, 1024, nullptr, 32768, 1024, 512);
            G(7, fbuf, 1024, w2T + 1024, 2048, nullptr, nullptr, nullptr, dlt, 512, nullptr, 32768, 512, 1024);
            add_bf16<<<8192, 256, 0, stream>>>(x, dlt);
        }
    }

    // ---- classifier --------------------------------------------------------
    for (int st = 0; st < 2; ++st) {
        const u16* e = st ? e2 : e1;
        const u16* x = st ? x2 : x1;
        G(3, e, 512, fc1T, 1024, nullptr, nullptr, nullptr, accf, 512, nullptr, 32768, 512, 512);   // e-part, fp32
        G(4, x, 512, fc1T + 512, 1024, fc1_b, nullptr, nullptr, hcls, 512, accf, 32768, 512, 512);  // relu(e+i+b)
        G(3, hcls, 512, fc2T, 512, fc2_b, nullptr, nullptr, accf, 512, nullptr, 32768, 512, 512);   // fp32 t2
        pool_sum<<<512, 128, 0, stream>>>(accf, pcat, st * 512);
    }
    G(1, pcat, 1024, fc3T, 1024, fc3_b, nullptr, nullptr, fc3o, 512, nullptr, 128, 512, 1024);
    fc4_kernel<<<6, 64, 0, stream>>>(fc3o, fc4_w, fc4_b, out);
}

// Round 3
// 9379.852 us; speedup vs baseline: 1.1108x; 1.1108x over previous
//
#include <hip/hip_runtime.h>

// ============================================================================
// TransformerNLI forward on MI355X (gfx950).
// bf16 MFMA GEMMs (BK=64) with LayerNorm folded into projection weights.
// Workspace budget: 264,318,976 bytes (guarded).
// ============================================================================

using u16 = unsigned short;
using u32 = unsigned int;

typedef __bf16 bf16x8 __attribute__((ext_vector_type(8)));
typedef u16    u16x8  __attribute__((ext_vector_type(8)));
typedef float  f32x4  __attribute__((ext_vector_type(4)));

#define D_THRESH 3.8918203f   // log(2000/40 - 1)

__device__ __forceinline__ u16 f2bf(float f) {
    u32 u = __builtin_bit_cast(u32, f);
    u32 r = (u + 0x7fffu + ((u >> 16) & 1u)) >> 16;   // RNE
    return (u16)r;
}
__device__ __forceinline__ float bf2f(u16 h) {
    u32 u = ((u32)h) << 16;
    return __builtin_bit_cast(float, u);
}
__device__ __forceinline__ bf16x8 ld_bf8(const u16* p) {
    u16x8 v = *(const u16x8*)p;
    return __builtin_bit_cast(bf16x8, v);
}

// global -> LDS async copy, 16B per lane; LDS dest = wave-uniform base + lane*16
#define GLD_LDS(gptr, lptr)                                                     \
    __builtin_amdgcn_global_load_lds(                                           \
        (const __attribute__((address_space(1))) u32*)(gptr),                   \
        (__attribute__((address_space(3))) u32*)(lptr), 16, 0, 0)

// ---------------------------------------------------------------------------
// Weight prep: fp32 [K,N] -> bf16 [N,K], optional per-k gamma scale, batched z
// ---------------------------------------------------------------------------
__global__ __launch_bounds__(256) void transpose_to_bf16(
    const float* __restrict__ in, u16* __restrict__ out,
    const float* __restrict__ gamma, int K, int N)
{
    __shared__ float tile[32][33];
    const float* src = in  + (size_t)blockIdx.z * K * N;
    u16*         dst = out + (size_t)blockIdx.z * K * N;
    const float* gm  = gamma ? gamma + (size_t)blockIdx.z * K : nullptr;
    int n0 = blockIdx.x * 32, k0 = blockIdx.y * 32;
#pragma unroll
    for (int i = 0; i < 4; ++i) {
        int k = k0 + threadIdx.y + i * 8;
        tile[threadIdx.y + i * 8][threadIdx.x] = src[(size_t)k * N + n0 + threadIdx.x];
    }
    __syncthreads();
#pragma unroll
    for (int i = 0; i < 4; ++i) {
        int n = n0 + threadIdx.y + i * 8;
        int kk = k0 + threadIdx.x;
        float v = tile[threadIdx.x][threadIdx.y + i * 8];
        if (gm) v *= gm[kk];
        dst[(size_t)n * K + kk] = f2bf(v);
    }
}

// u/d init + K-parallel partial column sums (fixes 18-block starvation)
__global__ __launch_bounds__(256) void init_ud(
    const float* __restrict__ bias, float* __restrict__ u, float* __restrict__ d)
{
    int n = blockIdx.x * 256 + threadIdx.x;
    u[n] = 0.f; d[n] = bias[n];
}

__global__ __launch_bounds__(256) void colsum_part(
    const float* __restrict__ W, const float* __restrict__ gamma,
    const float* __restrict__ beta, float* __restrict__ u, float* __restrict__ d,
    int K, int N)
{
    int n = blockIdx.x * 256 + threadIdx.x;
    int k0 = blockIdx.y * 32;
    const float* Wz = W + (size_t)blockIdx.z * K * N;
    const float* gz = gamma + (size_t)blockIdx.z * K;
    const float* bz = beta  + (size_t)blockIdx.z * K;
    float su = 0.f, sd = 0.f;
#pragma unroll 4
    for (int k = k0; k < k0 + 32; ++k) {
        float w = Wz[(size_t)k * N + n];
        su += gz[k] * w;
        sd += bz[k] * w;
    }
    atomicAdd(&u[(size_t)blockIdx.z * N + n], su);
    atomicAdd(&d[(size_t)blockIdx.z * N + n], sd);
}

// per-row (mean, rstd) of bf16 [M,512]
__global__ __launch_bounds__(256) void row_stats(
    const u16* __restrict__ x, float2* __restrict__ st)
{
    const int lane = threadIdx.x & 63, w = threadIdx.x >> 6;
    const size_t row = (size_t)blockIdx.x * 4 + w;
    union { uint4 v; u16 h[8]; } a;
    a.v = *(const uint4*)(x + row * 512 + lane * 8);
    float s = 0.f, sq = 0.f;
#pragma unroll
    for (int j = 0; j < 8; ++j) { float f = bf2f(a.h[j]); s += f; sq += f * f; }
#pragma unroll
    for (int off = 1; off < 64; off <<= 1) {
        s  += __shfl_xor(s,  off, 64);
        sq += __shfl_xor(sq, off, 64);
    }
    if (lane == 0) {
        float m  = s * (1.f / 512.f);
        float vr = sq * (1.f / 512.f) - m * m;
        st[row] = make_float2(m, rsqrtf(vr + 1e-5f));
    }
}

// ---------------------------------------------------------------------------
// GEMM: C[M,N] = epi(A[M,K](bf16,lda) @ BT[N,K](bf16,ldb)^T)   BK=64
// EPI: 0 bf16=acc+b | 1 bf16=relu(acc+b) | 2 bf16 C+=acc+b | 3 f32=acc(+b)
//      4 bf16=relu(resf+acc+b) | 5 bf16=rs*acc-rs*m*u[n]+d[n] | 6 relu(5)
//      8 bf16 C+=acc+res16
// ---------------------------------------------------------------------------
template<int EPI>
__global__ __launch_bounds__(256) void gemm_bt(
    const u16* __restrict__ A, int lda,
    const u16* __restrict__ BT, int ldb,
    const float* __restrict__ bias,      // EPI5/6: the d[] vector
    const float* __restrict__ u,
    const float2* __restrict__ st,
    void* __restrict__ Cv, int ldc,
    const float* __restrict__ resf,
    const u16* __restrict__ res16,
    int M, int N, int K)
{
    __shared__ u16 As[128 * 64];
    __shared__ u16 Bs[128 * 64];
    const int tid  = threadIdx.x;
    const int lane = tid & 63;
    const int w    = tid >> 6;
    const int wm   = w >> 1, wn = w & 1;
    const int m0   = blockIdx.y * 128, n0 = blockIdx.x * 128;
    const int g    = lane & 15, q = lane >> 4;

    const f32x4 fz = {0.f, 0.f, 0.f, 0.f};
    f32x4 acc[4][4];
#pragma unroll
    for (int i = 0; i < 4; ++i)
#pragma unroll
        for (int j = 0; j < 4; ++j) acc[i][j] = fz;

    for (int kt = 0; kt < K; kt += 64) {
#pragma unroll
        for (int i = 0; i < 4; ++i) {
            int c = (w * 4 + i) * 64 + lane;     // 16B chunk id; 8 chunks/row
            int r = c >> 3, cq = c & 7;
            GLD_LDS(A  + (size_t)(m0 + r) * lda + kt + cq * 8, As + (size_t)(w * 4 + i) * 512);
            GLD_LDS(BT + (size_t)(n0 + r) * ldb + kt + cq * 8, Bs + (size_t)(w * 4 + i) * 512);
        }
        __syncthreads();
#pragma unroll
        for (int ks = 0; ks < 2; ++ks) {
            bf16x8 af[4], bfr[4];
#pragma unroll
            for (int i = 0; i < 4; ++i) af[i]  = ld_bf8(As + (wm * 64 + i * 16 + g) * 64 + ks * 32 + q * 8);
#pragma unroll
            for (int j = 0; j < 4; ++j) bfr[j] = ld_bf8(Bs + (wn * 64 + j * 16 + g) * 64 + ks * 32 + q * 8);
#pragma unroll
            for (int i = 0; i < 4; ++i)
#pragma unroll
                for (int j = 0; j < 4; ++j)
                    acc[i][j] = __builtin_amdgcn_mfma_f32_16x16x32_bf16(af[i], bfr[j], acc[i][j], 0, 0, 0);
        }
        __syncthreads();
    }
    // epilogue: row = m0+wm*64+i*16+q*4+r, col = n0+wn*64+j*16+g
#pragma unroll
    for (int j = 0; j < 4; ++j) {
        int col  = n0 + wn * 64 + j * 16 + g;
        float bj = bias ? bias[col] : 0.f;
        float un = (EPI == 5 || EPI == 6) ? u[col] : 0.f;
#pragma unroll
        for (int i = 0; i < 4; ++i) {
            int rb = m0 + wm * 64 + i * 16 + q * 4;
#pragma unroll
            for (int r = 0; r < 4; ++r) {
                float v = acc[i][j][r];
                size_t idx = (size_t)(rb + r) * ldc + col;
                if (EPI == 5 || EPI == 6) {
                    float2 s2 = st[rb + r];
                    v = s2.y * v - s2.y * s2.x * un + bj;
                } else {
                    v += bj;
                }
                if (EPI == 1 || EPI == 6) v = fmaxf(v, 0.f);
                if (EPI == 4) v = fmaxf(resf[idx] + v, 0.f);
                if (EPI == 2) v += bf2f(((u16*)Cv)[idx]);
                if (EPI == 8) v += bf2f(((u16*)Cv)[idx]) + bf2f(res16[idx]);
                if (EPI == 3) ((float*)Cv)[idx] = v;
                else          ((u16*)Cv)[idx]   = f2bf(v);
            }
        }
    }
}

// ---------------------------------------------------------------------------
// Thresholded attention. Token row = s*128+b. One block = (b, h, 64 q-rows).
// Q[lq], K/V[lkv] strided; ctx written to O[lo] (may equal Q: block-disjoint).
// p = (s >= smax - D) ? exp(s - smax) : 0 ; out = (P V)/sum p
// ---------------------------------------------------------------------------
__global__ __launch_bounds__(256) void attn_kernel(
    const u16* __restrict__ Q, int lq,
    const u16* __restrict__ Kp, const u16* __restrict__ Vp, int lkv,
    u16* __restrict__ O, int lo)
{
    __shared__ u16 smem[32768];          // 64 KB
    u16* Ks  = smem;                     // [256][64]
    u16* Qs  = smem + 16384;             // [64][64]
    u16* Ps  = smem;                     // [64][256]  (phase 2)
    u16* VTs = smem + 16384;             // [64][256]

    const int tid = threadIdx.x, lane = tid & 63, w = tid >> 6;
    const int g = lane & 15, qd = lane >> 4;
    const int q0 = blockIdx.x * 64;
    const int b = blockIdx.y >> 3, h = blockIdx.y & 7;

#pragma unroll
    for (int i = 0; i < 8; ++i) {
        int c = (w * 8 + i) * 64 + lane;
        int r = c >> 3, cq = c & 7;
        GLD_LDS(Kp + (size_t)(r * 128 + b) * lkv + h * 64 + cq * 8,
                Ks + (size_t)(w * 8 + i) * 512);
    }
#pragma unroll
    for (int i = 0; i < 2; ++i) {
        int c = (w * 2 + i) * 64 + lane;
        int r = c >> 3, cq = c & 7;
        GLD_LDS(Q + (size_t)((q0 + r) * 128 + b) * lq + h * 64 + cq * 8,
                Qs + (size_t)(w * 2 + i) * 512);
    }
    __syncthreads();

    const f32x4 fz = {0.f, 0.f, 0.f, 0.f};
    f32x4 s[16];
#pragma unroll
    for (int t = 0; t < 16; ++t) s[t] = fz;
#pragma unroll
    for (int ks = 0; ks < 2; ++ks) {
        bf16x8 aq = ld_bf8(Qs + (w * 16 + g) * 64 + ks * 32 + qd * 8);
#pragma unroll
        for (int t = 0; t < 16; ++t) {
            bf16x8 bk = ld_bf8(Ks + (t * 16 + g) * 64 + ks * 32 + qd * 8);
            s[t] = __builtin_amdgcn_mfma_f32_16x16x32_bf16(aq, bk, s[t], 0, 0, 0);
        }
    }
    __syncthreads();   // Ks/Qs now free

    union { uint4 v; u16 us[8]; } vch[8];
#pragma unroll
    for (int i = 0; i < 8; ++i) {
        int c = i * 256 + tid;
        int r = c >> 3, cq = c & 7;
        vch[i].v = *(const uint4*)(Vp + (size_t)(r * 128 + b) * lkv + h * 64 + cq * 8);
    }

    float mrow[4] = {-1e30f, -1e30f, -1e30f, -1e30f};
#pragma unroll
    for (int t = 0; t < 16; ++t)
#pragma unroll
        for (int r = 0; r < 4; ++r) mrow[r] = fmaxf(mrow[r], s[t][r]);
#pragma unroll
    for (int off = 1; off < 16; off <<= 1)
#pragma unroll
        for (int r = 0; r < 4; ++r) mrow[r] = fmaxf(mrow[r], __shfl_xor(mrow[r], off, 64));
#pragma unroll
    for (int r = 0; r < 4; ++r) mrow[r] *= 0.125f;

    float l[4] = {0.f, 0.f, 0.f, 0.f};
#pragma unroll
    for (int t = 0; t < 16; ++t)
#pragma unroll
        for (int r = 0; r < 4; ++r) {
            float sc = s[t][r] * 0.125f;
            float p  = (sc >= mrow[r] - D_THRESH) ? __expf(sc - mrow[r]) : 0.f;
            u16 pb = f2bf(p);
            l[r] += bf2f(pb);
            Ps[(w * 16 + qd * 4 + r) * 256 + t * 16 + g] = pb;
        }
#pragma unroll
    for (int off = 1; off < 16; off <<= 1)
#pragma unroll
        for (int r = 0; r < 4; ++r) l[r] += __shfl_xor(l[r], off, 64);

#pragma unroll
    for (int i = 0; i < 8; ++i) {
        int c = i * 256 + tid;
        int r = c >> 3, cq = c & 7;
#pragma unroll
        for (int j = 0; j < 8; ++j) VTs[(cq * 8 + j) * 256 + r] = vch[i].us[j];
    }
    __syncthreads();

    f32x4 o[4];
#pragma unroll
    for (int nt = 0; nt < 4; ++nt) o[nt] = fz;
#pragma unroll
    for (int ks = 0; ks < 8; ++ks) {
        bf16x8 ap = ld_bf8(Ps + (w * 16 + g) * 256 + ks * 32 + qd * 8);
#pragma unroll
        for (int nt = 0; nt < 4; ++nt) {
            bf16x8 bv = ld_bf8(VTs + (nt * 16 + g) * 256 + ks * 32 + qd * 8);
            o[nt] = __builtin_amdgcn_mfma_f32_16x16x32_bf16(ap, bv, o[nt], 0, 0, 0);
        }
    }
    float rl[4];
#pragma unroll
    for (int r = 0; r < 4; ++r) rl[r] = 1.f / l[r];
#pragma unroll
    for (int nt = 0; nt < 4; ++nt)
#pragma unroll
        for (int r = 0; r < 4; ++r) {
            int srow = q0 + w * 16 + qd * 4 + r;
            O[(size_t)(srow * 128 + b) * lo + h * 64 + nt * 16 + g] = f2bf(o[nt][r] * rl[r]);
        }
}

// ---------------------------------------------------------------------------
// elementwise / small kernels
// ---------------------------------------------------------------------------
__global__ __launch_bounds__(256) void build_pe(float* __restrict__ pe) {
    int idx = blockIdx.x * 256 + threadIdx.x;   // 256*512
    int e = idx & 511, s = idx >> 9;
    int j = e >> 1;
    float fr = __expf((float)(2 * j) * (-0.017988946f));   // -ln(10000)/512
    float ph = (float)s * fr;
    pe[idx] = (e & 1) ? cosf(ph) : sinf(ph);
}

__global__ __launch_bounds__(256) void add_pe_bf16(
    const float* __restrict__ in, const float* __restrict__ pe, u16* __restrict__ out)
{
    size_t idx = (size_t)blockIdx.x * 256 + threadIdx.x;   // 32768*512
    int e = (int)(idx & 511);
    int s = (int)(idx >> 16);
    out[idx] = f2bf(in[idx] + pe[(s << 9) | e]);
}

__global__ __launch_bounds__(128) void pool_sum(
    const float* __restrict__ t2, u16* __restrict__ pcat, int colofs)
{
    int b = blockIdx.x >> 2, ec = blockIdx.x & 3;
    int e = ec * 128 + threadIdx.x;
    float acc = 0.f;
    for (int s = 0; s < 256; ++s) acc += t2[(size_t)(s * 128 + b) * 512 + e];
    pcat[b * 1024 + colofs + e] = f2bf(acc * 0.0625f);     // / sqrt(256)
}

__global__ __launch_bounds__(64) void fc4_kernel(
    const u16* __restrict__ a, const float* __restrict__ w,
    const float* __restrict__ bias, float* __restrict__ out)
{
    int id = blockIdx.x * 64 + threadIdx.x;                // 384 = 128*3
    if (id >= 384) return;
    int b = id / 3, l = id % 3;
    float acc = bias[l];
    for (int k = 0; k < 512; ++k) acc += bf2f(a[b * 512 + k]) * w[k * 3 + l];
    out[id] = acc;
}

__global__ __launch_bounds__(64) void sentinel_kernel(float* __restrict__ out) {
    int i = blockIdx.x * 64 + threadIdx.x;
    if (i < 384) out[i] = -12345.0f;
}

// ===========================================================================
extern "C" void kernel_launch(void* const* d_in, const int* in_sizes, int n_in,
                              void* d_out, int out_size, void* d_ws, size_t ws_size,
                              hipStream_t stream) {
    (void)in_sizes; (void)n_in; (void)out_size;

    const float* x_1       = (const float*)d_in[0];
    const float* x_2       = (const float*)d_in[1];
    const float* enc_ln1_g = (const float*)d_in[2];
    const float* enc_ln1_b = (const float*)d_in[3];
    const float* enc_Wqkv  = (const float*)d_in[4];
    const float* enc_bqkv  = (const float*)d_in[5];
    const float* enc_Wo    = (const float*)d_in[6];
    const float* enc_bo    = (const float*)d_in[7];
    const float* enc_ln2_g = (const float*)d_in[8];
    const float* enc_ln2_b = (const float*)d_in[9];
    const float* enc_W1    = (const float*)d_in[10];
    const float* enc_b1    = (const float*)d_in[11];
    const float* enc_W2    = (const float*)d_in[12];
    const float* enc_b2    = (const float*)d_in[13];
    const float* isa_ln_g  = (const float*)d_in[14];
    const float* isa_ln_b  = (const float*)d_in[15];
    const float* isa_Wqkv  = (const float*)d_in[16];
    const float* isa_bqkv  = (const float*)d_in[17];
    const float* isa_Wo    = (const float*)d_in[18];
    const float* isa_bo    = (const float*)d_in[19];
    const float* iea_ln_g  = (const float*)d_in[20];
    const float* iea_ln_b  = (const float*)d_in[21];
    const float* iea_Wqkv  = (const float*)d_in[22];
    const float* iea_bqkv  = (const float*)d_in[23];
    const float* iea_Wo    = (const float*)d_in[24];
    const float* iea_bo    = (const float*)d_in[25];
    const float* iff_ln_g  = (const float*)d_in[26];
    const float* iff_ln_b  = (const float*)d_in[27];
    const float* int_W1    = (const float*)d_in[28];
    const float* int_b1    = (const float*)d_in[29];
    const float* int_W2    = (const float*)d_in[30];
    const float* int_b2    = (const float*)d_in[31];
    const float* fc1_w     = (const float*)d_in[32];
    const float* fc1_b     = (const float*)d_in[33];
    const float* fc2_w     = (const float*)d_in[34];
    const float* fc2_b     = (const float*)d_in[35];
    const float* fc3_w     = (const float*)d_in[36];
    const float* fc3_b     = (const float*)d_in[37];
    const float* fc4_w     = (const float*)d_in[38];
    const float* fc4_b     = (const float*)d_in[39];
    float* out = (float*)d_out;

    const size_t WS_NEED = 264318976;
    if (ws_size < WS_NEED) {                 // diagnostic: absmax ~12345 => ws too small
        sentinel_kernel<<<6, 64, 0, stream>>>(out);
        return;
    }

    char* ws = (char*)d_ws;
    // ---- persistent transposed weights (byte offsets) ----------------------
    u16* isaQKV = (u16*)(ws + 0);         // [3][1536][512]
    u16* isaWO  = (u16*)(ws + 4718592);   // [3][512][512]
    u16* ieaQKV = (u16*)(ws + 6291456);
    u16* ieaWO  = (u16*)(ws + 11010048);
    u16* intW1  = (u16*)(ws + 12582912);  // [3][2048][512]
    u16* intW2  = (u16*)(ws + 18874368);  // [3][512][2048]
    u16* fc1T   = (u16*)(ws + 25165824);  // [512][1024]
    u16* fc2T   = (u16*)(ws + 26214400);  // [512][512]
    u16* fc3T   = (u16*)(ws + 26738688);  // [512][1024]
    float* UD   = (float*)(ws + 27787264);
    float* enc_qkv_u = UD;                // [3][1536]
    float* enc_qkv_d = UD + 4608;
    float* enc_w1_u  = UD + 9216;         // [3][2048]
    float* enc_w1_d  = UD + 15360;
    float* isa_qkv_u = UD + 21504;
    float* isa_qkv_d = UD + 26112;
    float* iea_qkv_u = UD + 30720;
    float* iea_qkv_d = UD + 35328;
    float* int_w1_u  = UD + 39936;
    float* int_w1_d  = UD + 46080;
    float2* stats1 = (float2*)(ws + 27996160);   // [32768]
    float2* stats2 = (float2*)(ws + 28258304);
    float*  pe     = (float*)(ws + 28520448);    // [256,512]
    u16*    pcat   = (u16*)(ws + 29044736);      // [128,1024]
    u16*    fc3o   = (u16*)(ws + 29306880);      // [128,512]
    u16*    x1     = (u16*)(ws + 29437952);      // [32768,512] bf16 residual
    u16*    x2     = (u16*)(ws + 62992384);
    // EREG: during encoder holds enc transposed weights; afterwards e1/e2
    u16* encQKV = (u16*)(ws + 96546816);             // [3][1536][512]
    u16* encWO  = (u16*)(ws + 96546816 + 4718592);   // [3][512][512]
    u16* encW1  = (u16*)(ws + 96546816 + 6291456);   // [3][2048][512]
    u16* encW2  = (u16*)(ws + 96546816 + 12582912);  // [3][512][2048]
    u16* e1     = (u16*)(ws + 96546816);             // [32768,512]
    u16* e2     = (u16*)(ws + 96546816 + 33554432);
    // BIG scratch: 100 MB, phase-dependent
    u16*   qkv  = (u16*)(ws + 163655680);            // [32768,1536]
    u16*   B0   = (u16*)(ws + 163655680);            // [32768,512]
    u16*   B1   = (u16*)(ws + 163655680 + 33554432); // [32768,1024]
    u16*   fbuf = (u16*)(ws + 163655680);            // [32768,1024]
    u16*   dlt  = (u16*)(ws + 163655680 + 67108864); // [32768,512]
    float* accf = (float*)(ws + 163655680);          // [32768,512] fp32
    u16*   hcls = (u16*)(ws + 163655680 + 67108864); // [32768,512]

    // ---- weight prep -------------------------------------------------------
    auto TR = [&](const float* in, u16* o, const float* g, int K, int N, int L) {
        transpose_to_bf16<<<dim3(N / 32, K / 32, L), dim3(32, 8), 0, stream>>>(in, o, g, K, N);
    };
    TR(enc_Wqkv, encQKV, enc_ln1_g, 512, 1536, 3);
    TR(enc_Wo,   encWO,  nullptr,   512, 512,  3);
    TR(enc_W1,   encW1,  enc_ln2_g, 512, 2048, 3);
    TR(enc_W2,   encW2,  nullptr,   2048, 512, 3);
    TR(isa_Wqkv, isaQKV, isa_ln_g,  512, 1536, 3);
    TR(isa_Wo,   isaWO,  nullptr,   512, 512,  3);
    TR(iea_Wqkv, ieaQKV, iea_ln_g,  512, 1536, 3);
    TR(iea_Wo,   ieaWO,  nullptr,   512, 512,  3);
    TR(int_W1,   intW1,  iff_ln_g,  512, 2048, 3);
    TR(int_W2,   intW2,  nullptr,   2048, 512, 3);
    TR(fc1_w, fc1T, nullptr, 1024, 512, 1);
    TR(fc2_w, fc2T, nullptr, 512,  512, 1);
    TR(fc3_w, fc3T, nullptr, 1024, 512, 1);

    auto CS = [&](const float* W, const float* g, const float* b, const float* bias,
                  float* u, float* d, int K, int N, int L) {
        init_ud<<<N * L / 256, 256, 0, stream>>>(bias, u, d);
        colsum_part<<<dim3(N / 256, K / 32, L), 256, 0, stream>>>(W, g, b, u, d, K, N);
    };
    CS(enc_Wqkv, enc_ln1_g, enc_ln1_b, enc_bqkv, enc_qkv_u, enc_qkv_d, 512, 1536, 3);
    CS(enc_W1,   enc_ln2_g, enc_ln2_b, enc_b1,   enc_w1_u,  enc_w1_d,  512, 2048, 3);
    CS(isa_Wqkv, isa_ln_g,  isa_ln_b,  isa_bqkv, isa_qkv_u, isa_qkv_d, 512, 1536, 3);
    CS(iea_Wqkv, iea_ln_g,  iea_ln_b,  iea_bqkv, iea_qkv_u, iea_qkv_d, 512, 1536, 3);
    CS(int_W1,   iff_ln_g,  iff_ln_b,  int_b1,   int_w1_u,  int_w1_d,  512, 2048, 3);

    build_pe<<<512, 256, 0, stream>>>(pe);
    add_pe_bf16<<<65536, 256, 0, stream>>>(x_1, pe, x1);
    add_pe_bf16<<<65536, 256, 0, stream>>>(x_2, pe, x2);

    // ---- launch helpers ----------------------------------------------------
    auto G = [&](int epi, const u16* A, int lda, const u16* BT, int ldb,
                 const float* bias, const float* uu, const float2* stt,
                 void* C, int ldc, const float* resf, const u16* res16,
                 int M, int N, int K) {
        dim3 grid(N / 128, M / 128);
        switch (epi) {
        case 0: gemm_bt<0><<<grid, 256, 0, stream>>>(A, lda, BT, ldb, bias, uu, stt, C, ldc, resf, res16, M, N, K); break;
        case 1: gemm_bt<1><<<grid, 256, 0, stream>>>(A, lda, BT, ldb, bias, uu, stt, C, ldc, resf, res16, M, N, K); break;
        case 2: gemm_bt<2><<<grid, 256, 0, stream>>>(A, lda, BT, ldb, bias, uu, stt, C, ldc, resf, res16, M, N, K); break;
        case 3: gemm_bt<3><<<grid, 256, 0, stream>>>(A, lda, BT, ldb, bias, uu, stt, C, ldc, resf, res16, M, N, K); break;
        case 4: gemm_bt<4><<<grid, 256, 0, stream>>>(A, lda, BT, ldb, bias, uu, stt, C, ldc, resf, res16, M, N, K); break;
        case 5: gemm_bt<5><<<grid, 256, 0, stream>>>(A, lda, BT, ldb, bias, uu, stt, C, ldc, resf, res16, M, N, K); break;
        case 6: gemm_bt<6><<<grid, 256, 0, stream>>>(A, lda, BT, ldb, bias, uu, stt, C, ldc, resf, res16, M, N, K); break;
        case 8: gemm_bt<8><<<grid, 256, 0, stream>>>(A, lda, BT, ldb, bias, uu, stt, C, ldc, resf, res16, M, N, K); break;
        }
    };
    auto STATS = [&](const u16* x, float2* stt) {
        row_stats<<<8192, 256, 0, stream>>>(x, stt);
    };
    auto ATT = [&](const u16* Qp, int lq, const u16* Kp, const u16* Vp, int lkv,
                   u16* Op, int lo) {
        attn_kernel<<<dim3(4, 1024), 256, 0, stream>>>(Qp, lq, Kp, Vp, lkv, Op, lo);
    };

    // self-attn + FFN block (encoder & interaction share the shape)
    auto self_block = [&](u16* x, u16* wqkvT, const float* qu, const float* qd,
                          u16* woT, const float* bo,
                          u16* w1T, const float* w1u, const float* w1d,
                          u16* w2T, const float* b2, bool do_ffn) {
        STATS(x, stats1);
        G(5, x, 512, wqkvT, 512, qd, qu, stats1, qkv, 1536, nullptr, nullptr, 32768, 1536, 512);
        ATT(qkv, 1536, qkv + 512, qkv + 1024, 1536, qkv, 1536);
        G(2, qkv, 1536, woT, 512, bo, nullptr, nullptr, x, 512, nullptr, nullptr, 32768, 512, 512);
        if (do_ffn) {
            STATS(x, stats1);
            G(6, x, 512, w1T, 512, w1d, w1u, stats1, fbuf, 1024, nullptr, nullptr, 32768, 1024, 512);
            G(0, fbuf, 1024, w2T, 2048, b2, nullptr, nullptr, dlt, 512, nullptr, nullptr, 32768, 512, 1024);
            G(6, x, 512, w1T + 1024 * 512, 512, w1d + 1024, w1u + 1024, stats1, fbuf, 1024, nullptr, nullptr, 32768, 1024, 512);
            G(8, fbuf, 1024, w2T + 1024, 2048, nullptr, nullptr, nullptr, x, 512, nullptr, dlt, 32768, 512, 1024);
        }
    };

    // ---- Siamese encoder ---------------------------------------------------
    for (int i = 0; i < 3; ++i)
        for (int st = 0; st < 2; ++st)
            self_block(st ? x2 : x1,
                       encQKV + (size_t)i * 786432, enc_qkv_u + i * 1536, enc_qkv_d + i * 1536,
                       encWO + (size_t)i * 262144, enc_bo + i * 512,
                       encW1 + (size_t)i * 1048576, enc_w1_u + i * 2048, enc_w1_d + i * 2048,
                       encW2 + (size_t)i * 1048576, enc_b2 + i * 512, true);

    // snapshots (enc weights in EREG are dead now)
    hipMemcpyAsync(e1, x1, 33554432, hipMemcpyDeviceToDevice, stream);
    hipMemcpyAsync(e2, x2, 33554432, hipMemcpyDeviceToDevice, stream);

    // ---- interaction stack -------------------------------------------------
    for (int i = 0; i < 3; ++i) {
        // self-attn (isa), no FFN inside
        for (int st = 0; st < 2; ++st)
            self_block(st ? x2 : x1,
                       isaQKV + (size_t)i * 786432, isa_qkv_u + i * 1536, isa_qkv_d + i * 1536,
                       isaWO + (size_t)i * 262144, isa_bo + i * 512,
                       nullptr, nullptr, nullptr, nullptr, nullptr, false);
        // cross-attn (iea): h1,h2 from pre-update x1,x2
        u16* qT  = ieaQKV + (size_t)i * 786432;
        u16* kvT = qT + 512 * 512;
        const float* qu = iea_qkv_u + i * 1536;
        const float* qd = iea_qkv_d + i * 1536;
        STATS(x2, stats2);
        G(5, x2, 512, kvT, 512, qd + 512, qu + 512, stats2, B1, 1024, nullptr, nullptr, 32768, 1024, 512); // kv2
        STATS(x1, stats1);
        G(5, x1, 512, qT, 512, qd, qu, stats1, B0, 512, nullptr, nullptr, 32768, 512, 512);               // q1
        ATT(B0, 512, B1, B1 + 512, 1024, B0, 512);                                                        // ctx1
        G(5, x1, 512, kvT, 512, qd + 512, qu + 512, stats1, B1, 1024, nullptr, nullptr, 32768, 1024, 512); // kv1 (x1 old)
        G(2, B0, 512, ieaWO + (size_t)i * 262144, 512, iea_bo + i * 512, nullptr, nullptr,
          x1, 512, nullptr, nullptr, 32768, 512, 512);                                                    // x1 += y1
        G(5, x2, 512, qT, 512, qd, qu, stats2, B0, 512, nullptr, nullptr, 32768, 512, 512);               // q2 (x2 old)
        ATT(B0, 512, B1, B1 + 512, 1024, B0, 512);                                                        // ctx2
        G(2, B0, 512, ieaWO + (size_t)i * 262144, 512, iea_bo + i * 512, nullptr, nullptr,
          x2, 512, nullptr, nullptr, 32768, 512, 512);                                                    // x2 += y2
        // FFN (int/iff)
        for (int st = 0; st < 2; ++st) {
            u16* x = st ? x2 : x1;
            STATS(x, stats1);
            u16* w1T = intW1 + (size_t)i * 1048576;
            u16* w2T = intW2 + (size_t)i * 1048576;
            const float* w1u = int_w1_u + i * 2048;
            const float* w1d = int_w1_d + i * 2048;
            G(6, x, 512, w1T, 512, w1d, w1u, stats1, fbuf, 1024, nullptr, nullptr, 32768, 1024, 512);
            G(0, fbuf, 1024, w2T, 2048, int_b2 + i * 512, nullptr, nullptr, dlt, 512, nullptr, nullptr, 32768, 512, 1024);
            G(6, x, 512, w1T + 1024 * 512, 512, w1d + 1024, w1u + 1024, stats1, fbuf, 1024, nullptr, nullptr, 32768, 1024, 512);
            G(8, fbuf, 1024, w2T + 1024, 2048, nullptr, nullptr, nullptr, x, 512, nullptr, dlt, 32768, 512, 1024);
        }
    }

    // ---- classifier --------------------------------------------------------
    for (int st = 0; st < 2; ++st) {
        const u16* e = st ? e2 : e1;
        const u16* x = st ? x2 : x1;
        G(3, e, 512, fc1T, 1024, nullptr, nullptr, nullptr, accf, 512, nullptr, nullptr, 32768, 512, 512);   // e-part, fp32
        G(4, x, 512, fc1T + 512, 1024, fc1_b, nullptr, nullptr, hcls, 512, accf, nullptr, 32768, 512, 512);  // relu(e+i+b)
        G(3, hcls, 512, fc2T, 512, fc2_b, nullptr, nullptr, accf, 512, nullptr, nullptr, 32768, 512, 512);   // fp32 t2
        pool_sum<<<512, 128, 0, stream>>>(accf, pcat, st * 512);
    }
    G(1, pcat, 1024, fc3T, 1024, fc3_b, nullptr, nullptr, fc3o, 512, nullptr, nullptr, 128, 512, 1024);
    fc4_kernel<<<6, 64, 0, stream>>>(fc3o, fc4_w, fc4_b, out);
}

// Round 4
// 7924.819 us; speedup vs baseline: 1.3148x; 1.1836x over previous
//
#include <hip/hip_runtime.h>

// ============================================================================
// TransformerNLI forward on MI355X (gfx950).
// bf16 MFMA GEMMs (BK=64, vectorized LDS-staged epilogue) with LayerNorm
// folded into projection weights. Attention: one 512-thread block per (b,h),
// K persistent in LDS, kv-quartered PV with conflict-free VT staging.
// Workspace budget: 264,318,976 bytes (guarded).
// ============================================================================

using u16 = unsigned short;
using u32 = unsigned int;

typedef __bf16 bf16x8 __attribute__((ext_vector_type(8)));
typedef u16    u16x8  __attribute__((ext_vector_type(8)));
typedef float  f32x4  __attribute__((ext_vector_type(4)));

#define D_THRESH 3.8918203f   // log(2000/40 - 1)

__device__ __forceinline__ u16 f2bf(float f) {
    u32 u = __builtin_bit_cast(u32, f);
    u32 r = (u + 0x7fffu + ((u >> 16) & 1u)) >> 16;   // RNE
    return (u16)r;
}
__device__ __forceinline__ float bf2f(u16 h) {
    u32 u = ((u32)h) << 16;
    return __builtin_bit_cast(float, u);
}
__device__ __forceinline__ bf16x8 ld_bf8(const u16* p) {
    u16x8 v = *(const u16x8*)p;
    return __builtin_bit_cast(bf16x8, v);
}

// global -> LDS async copy, 16B per lane; LDS dest = wave-uniform base + lane*16
#define GLD_LDS(gptr, lptr)                                                     \
    __builtin_amdgcn_global_load_lds(                                           \
        (const __attribute__((address_space(1))) u32*)(gptr),                   \
        (__attribute__((address_space(3))) u32*)(lptr), 16, 0, 0)

// ---------------------------------------------------------------------------
// Weight prep: fp32 [K,N] -> bf16 [N,K], optional per-k gamma scale, batched z
// ---------------------------------------------------------------------------
__global__ __launch_bounds__(256) void transpose_to_bf16(
    const float* __restrict__ in, u16* __restrict__ out,
    const float* __restrict__ gamma, int K, int N)
{
    __shared__ float tile[32][33];
    const float* src = in  + (size_t)blockIdx.z * K * N;
    u16*         dst = out + (size_t)blockIdx.z * K * N;
    const float* gm  = gamma ? gamma + (size_t)blockIdx.z * K : nullptr;
    int n0 = blockIdx.x * 32, k0 = blockIdx.y * 32;
#pragma unroll
    for (int i = 0; i < 4; ++i) {
        int k = k0 + threadIdx.y + i * 8;
        tile[threadIdx.y + i * 8][threadIdx.x] = src[(size_t)k * N + n0 + threadIdx.x];
    }
    __syncthreads();
#pragma unroll
    for (int i = 0; i < 4; ++i) {
        int n = n0 + threadIdx.y + i * 8;
        int kk = k0 + threadIdx.x;
        float v = tile[threadIdx.x][threadIdx.y + i * 8];
        if (gm) v *= gm[kk];
        dst[(size_t)n * K + kk] = f2bf(v);
    }
}

// u/d init + K-parallel partial column sums
__global__ __launch_bounds__(256) void init_ud(
    const float* __restrict__ bias, float* __restrict__ u, float* __restrict__ d)
{
    int n = blockIdx.x * 256 + threadIdx.x;
    u[n] = 0.f; d[n] = bias[n];
}

__global__ __launch_bounds__(256) void colsum_part(
    const float* __restrict__ W, const float* __restrict__ gamma,
    const float* __restrict__ beta, float* __restrict__ u, float* __restrict__ d,
    int K, int N)
{
    int n = blockIdx.x * 256 + threadIdx.x;
    int k0 = blockIdx.y * 32;
    const float* Wz = W + (size_t)blockIdx.z * K * N;
    const float* gz = gamma + (size_t)blockIdx.z * K;
    const float* bz = beta  + (size_t)blockIdx.z * K;
    float su = 0.f, sd = 0.f;
#pragma unroll 4
    for (int k = k0; k < k0 + 32; ++k) {
        float w = Wz[(size_t)k * N + n];
        su += gz[k] * w;
        sd += bz[k] * w;
    }
    atomicAdd(&u[(size_t)blockIdx.z * N + n], su);
    atomicAdd(&d[(size_t)blockIdx.z * N + n], sd);
}

// per-row (mean, rstd) of bf16 [M,512]
__global__ __launch_bounds__(256) void row_stats(
    const u16* __restrict__ x, float2* __restrict__ st)
{
    const int lane = threadIdx.x & 63, w = threadIdx.x >> 6;
    const size_t row = (size_t)blockIdx.x * 4 + w;
    union { uint4 v; u16 h[8]; } a;
    a.v = *(const uint4*)(x + row * 512 + lane * 8);
    float s = 0.f, sq = 0.f;
#pragma unroll
    for (int j = 0; j < 8; ++j) { float f = bf2f(a.h[j]); s += f; sq += f * f; }
#pragma unroll
    for (int off = 1; off < 64; off <<= 1) {
        s  += __shfl_xor(s,  off, 64);
        sq += __shfl_xor(sq, off, 64);
    }
    if (lane == 0) {
        float m  = s * (1.f / 512.f);
        float vr = sq * (1.f / 512.f) - m * m;
        st[row] = make_float2(m, rsqrtf(vr + 1e-5f));
    }
}

// ---------------------------------------------------------------------------
// GEMM: C[M,N] = epi(A[M,K](bf16,lda) @ BT[N,K](bf16,ldb)^T)   BK=64
// EPI: 0 bf16=acc+b | 1 bf16=relu(acc+b) | 2 bf16 C+=acc+b | 3 f32=acc(+b)
//      4 bf16=relu(resf+acc+b) | 5 bf16=rs*acc-rs*m*u[n]+d[n] | 6 relu(5)
//      8 bf16 C+=acc+res16
// bf16-out EPIs use an LDS-staged vectorized (16B) epilogue.
// ---------------------------------------------------------------------------
template<int EPI>
__global__ __launch_bounds__(256) void gemm_bt(
    const u16* __restrict__ A, int lda,
    const u16* __restrict__ BT, int ldb,
    const float* __restrict__ bias,      // EPI5/6: the d[] vector
    const float* __restrict__ u,
    const float2* __restrict__ st,
    void* __restrict__ Cv, int ldc,
    const float* __restrict__ resf,
    const u16* __restrict__ res16,
    int M, int N, int K)
{
    __shared__ u16 smem[17408];          // 34816 B: As|Bs (32KB) then C-stage [128][136]
    u16* As = smem;
    u16* Bs = smem + 8192;
    const int tid  = threadIdx.x;
    const int lane = tid & 63;
    const int w    = tid >> 6;
    const int wm   = w >> 1, wn = w & 1;
    const int m0   = blockIdx.y * 128, n0 = blockIdx.x * 128;
    const int g    = lane & 15, q = lane >> 4;

    const f32x4 fz = {0.f, 0.f, 0.f, 0.f};
    f32x4 acc[4][4];
#pragma unroll
    for (int i = 0; i < 4; ++i)
#pragma unroll
        for (int j = 0; j < 4; ++j) acc[i][j] = fz;

    for (int kt = 0; kt < K; kt += 64) {
#pragma unroll
        for (int i = 0; i < 4; ++i) {
            int c = (w * 4 + i) * 64 + lane;     // 16B chunk id; 8 chunks/row
            int r = c >> 3, cq = c & 7;
            GLD_LDS(A  + (size_t)(m0 + r) * lda + kt + cq * 8, As + (size_t)(w * 4 + i) * 512);
            GLD_LDS(BT + (size_t)(n0 + r) * ldb + kt + cq * 8, Bs + (size_t)(w * 4 + i) * 512);
        }
        __syncthreads();
#pragma unroll
        for (int ks = 0; ks < 2; ++ks) {
            bf16x8 af[4], bfr[4];
#pragma unroll
            for (int i = 0; i < 4; ++i) af[i]  = ld_bf8(As + (wm * 64 + i * 16 + g) * 64 + ks * 32 + q * 8);
#pragma unroll
            for (int j = 0; j < 4; ++j) bfr[j] = ld_bf8(Bs + (wn * 64 + j * 16 + g) * 64 + ks * 32 + q * 8);
#pragma unroll
            for (int i = 0; i < 4; ++i)
#pragma unroll
                for (int j = 0; j < 4; ++j)
                    acc[i][j] = __builtin_amdgcn_mfma_f32_16x16x32_bf16(af[i], bfr[j], acc[i][j], 0, 0, 0);
        }
        __syncthreads();
    }

    if (EPI == 3 || EPI == 4) {
        // scalar epilogue (f32 outputs / f32 residual): classifier only
#pragma unroll
        for (int j = 0; j < 4; ++j) {
            int col  = n0 + wn * 64 + j * 16 + g;
            float bj = bias ? bias[col] : 0.f;
#pragma unroll
            for (int i = 0; i < 4; ++i) {
                int rb = m0 + wm * 64 + i * 16 + q * 4;
#pragma unroll
                for (int r = 0; r < 4; ++r) {
                    float v = acc[i][j][r] + bj;
                    size_t idx = (size_t)(rb + r) * ldc + col;
                    if (EPI == 4) { v = fmaxf(resf[idx] + v, 0.f); ((u16*)Cv)[idx] = f2bf(v); }
                    else          ((float*)Cv)[idx] = v;
                }
            }
        }
    } else {
        // stage transformed bf16 tile into LDS, then 16B global I/O
        u16* Cs = smem;                  // [128][136]
#pragma unroll
        for (int j = 0; j < 4; ++j) {
            int cl   = wn * 64 + j * 16 + g;
            float bj = bias ? bias[n0 + cl] : 0.f;
            float un = (EPI == 5 || EPI == 6) ? u[n0 + cl] : 0.f;
#pragma unroll
            for (int i = 0; i < 4; ++i) {
                int rl = wm * 64 + i * 16 + q * 4;
#pragma unroll
                for (int r = 0; r < 4; ++r) {
                    float v = acc[i][j][r];
                    if (EPI == 5 || EPI == 6) {
                        float2 s2 = st[m0 + rl + r];
                        v = s2.y * v - s2.y * s2.x * un + bj;
                    } else {
                        v += bj;
                    }
                    if (EPI == 1 || EPI == 6) v = fmaxf(v, 0.f);
                    Cs[(rl + r) * 136 + cl] = f2bf(v);
                }
            }
        }
        __syncthreads();
        const int cr = tid >> 4, cc = tid & 15;
#pragma unroll
        for (int rr = 0; rr < 8; ++rr) {
            int rl = cr * 8 + rr;
            size_t gidx = (size_t)(m0 + rl) * ldc + n0 + cc * 8;
            union { uint4 v; u16 h8[8]; } sv;
            sv.v = *(const uint4*)(Cs + rl * 136 + cc * 8);
            if (EPI == 2 || EPI == 8) {
                union { uint4 v; u16 h8[8]; } cv2, rv;
                cv2.v = *(const uint4*)((const u16*)Cv + gidx);
                if (EPI == 8) rv.v = *(const uint4*)(res16 + gidx);
#pragma unroll
                for (int jj = 0; jj < 8; ++jj) {
                    float v = bf2f(sv.h8[jj]) + bf2f(cv2.h8[jj]);
                    if (EPI == 8) v += bf2f(rv.h8[jj]);
                    sv.h8[jj] = f2bf(v);
                }
            }
            *(uint4*)((u16*)Cv + gidx) = sv.v;
        }
    }
}

// ---------------------------------------------------------------------------
// Thresholded attention. Token row = s*128+b. ONE block per (b,h), 512 thr.
// K persistent in LDS; Q loaded direct to A-frags; 2 sweeps x 128 q-rows;
// PV in 4 kv-quarters via padded P LDS + conflict-free VT staging.
// p = (s >= smax - D) ? exp(s - smax) : 0 ; out = (P V)/sum p
// ---------------------------------------------------------------------------
__global__ __launch_bounds__(512, 4) void attn_kernel(
    const u16* __restrict__ Q, int lq,
    const u16* __restrict__ Kp, const u16* __restrict__ Vp, int lkv,
    u16* __restrict__ O, int lo)
{
    __shared__ u16 smem[29696];          // 59392 B
    u16* Ks  = smem;                     // [256][64]   32768 B (persistent)
    u16* Ps  = smem + 16384;             // [128][72]   18432 B
    u16* VTs = smem + 25600;             // [64][64]     8192 B

    const int tid = threadIdx.x, lane = tid & 63, w = tid >> 6;
    const int g = lane & 15, qd = lane >> 4;
    const int b = blockIdx.x >> 3, h = blockIdx.x & 7;

    // stage K once: 512 thr x 16B x 4 iters = 32 KB
#pragma unroll
    for (int i = 0; i < 4; ++i) {
        int c = i * 512 + tid;
        int r = c >> 3, cq = c & 7;
        GLD_LDS(Kp + (size_t)(r * 128 + b) * lkv + h * 64 + cq * 8,
                Ks + (size_t)(i * 512 + w * 64) * 8);
    }
    __syncthreads();

    const f32x4 fz = {0.f, 0.f, 0.f, 0.f};
    for (int s = 0; s < 2; ++s) {
        const int qb = s * 128 + w * 16;     // wave's 16 q-rows this sweep

        // ---- QK^T: scores for 16 rows x 256 kv in regs -------------------
        f32x4 sc[16];
#pragma unroll
        for (int t = 0; t < 16; ++t) sc[t] = fz;
#pragma unroll
        for (int ks = 0; ks < 2; ++ks) {
            bf16x8 aq = ld_bf8(Q + (size_t)((qb + g) * 128 + b) * lq + h * 64 + ks * 32 + qd * 8);
#pragma unroll
            for (int t = 0; t < 16; ++t) {
                bf16x8 bk = ld_bf8(Ks + (t * 16 + g) * 64 + ks * 32 + qd * 8);
                sc[t] = __builtin_amdgcn_mfma_f32_16x16x32_bf16(aq, bk, sc[t], 0, 0, 0);
            }
        }

        // ---- softmax with threshold (row = qd*4+r, col = t*16+g) ---------
        float mrow[4] = {-1e30f, -1e30f, -1e30f, -1e30f};
#pragma unroll
        for (int t = 0; t < 16; ++t)
#pragma unroll
            for (int r = 0; r < 4; ++r) mrow[r] = fmaxf(mrow[r], sc[t][r]);
#pragma unroll
        for (int off = 1; off < 16; off <<= 1)
#pragma unroll
            for (int r = 0; r < 4; ++r) mrow[r] = fmaxf(mrow[r], __shfl_xor(mrow[r], off, 64));
#pragma unroll
        for (int r = 0; r < 4; ++r) mrow[r] *= 0.125f;

        float l[4] = {0.f, 0.f, 0.f, 0.f};
        u32 pk[16][2];
#pragma unroll
        for (int t = 0; t < 16; ++t)
#pragma unroll
            for (int r = 0; r < 4; ++r) {
                float scv = sc[t][r] * 0.125f;
                float p   = (scv >= mrow[r] - D_THRESH) ? __expf(scv - mrow[r]) : 0.f;
                u16 pb = f2bf(p);
                l[r] += bf2f(pb);
                if (r & 1) pk[t][r >> 1] |= ((u32)pb) << 16;
                else       pk[t][r >> 1]  = pb;
            }
#pragma unroll
        for (int off = 1; off < 16; off <<= 1)
#pragma unroll
            for (int r = 0; r < 4; ++r) l[r] += __shfl_xor(l[r], off, 64);

        // ---- PV over 4 kv-quarters ---------------------------------------
        f32x4 o[4];
#pragma unroll
        for (int nt = 0; nt < 4; ++nt) o[nt] = fz;
        for (int qt = 0; qt < 4; ++qt) {
            // P-quarter: wave's 16 rows x 64 kv
#pragma unroll
            for (int tt = 0; tt < 4; ++tt) {
                int t = qt * 4 + tt;
#pragma unroll
                for (int rh = 0; rh < 2; ++rh) {
                    u32 pv = pk[t][rh];
                    Ps[(w * 16 + qd * 4 + rh * 2)     * 72 + tt * 16 + g] = (u16)pv;
                    Ps[(w * 16 + qd * 4 + rh * 2 + 1) * 72 + tt * 16 + g] = (u16)(pv >> 16);
                }
            }
            // VT-quarter: lane=kv (conflict-free), wave owns d rows w*8..w*8+8
            {
                int kvr = qt * 64 + lane;
                union { uint4 v; u16 h8[8]; } vu;
                vu.v = *(const uint4*)(Vp + (size_t)(kvr * 128 + b) * lkv + h * 64 + w * 8);
#pragma unroll
                for (int jj = 0; jj < 8; ++jj) VTs[(w * 8 + jj) * 64 + lane] = vu.h8[jj];
            }
            __syncthreads();
#pragma unroll
            for (int st2 = 0; st2 < 2; ++st2) {
                bf16x8 ap = ld_bf8(Ps + (w * 16 + g) * 72 + st2 * 32 + qd * 8);
#pragma unroll
                for (int nt = 0; nt < 4; ++nt) {
                    bf16x8 bv = ld_bf8(VTs + (nt * 16 + g) * 64 + st2 * 32 + qd * 8);
                    o[nt] = __builtin_amdgcn_mfma_f32_16x16x32_bf16(ap, bv, o[nt], 0, 0, 0);
                }
            }
            __syncthreads();
        }

        float rl[4];
#pragma unroll
        for (int r = 0; r < 4; ++r) rl[r] = 1.f / l[r];
#pragma unroll
        for (int nt = 0; nt < 4; ++nt)
#pragma unroll
            for (int r = 0; r < 4; ++r) {
                int qrow = qb + qd * 4 + r;
                O[(size_t)(qrow * 128 + b) * lo + h * 64 + nt * 16 + g] = f2bf(o[nt][r] * rl[r]);
            }
    }
}

// ---------------------------------------------------------------------------
// elementwise / small kernels
// ---------------------------------------------------------------------------
__global__ __launch_bounds__(256) void build_pe(float* __restrict__ pe) {
    int idx = blockIdx.x * 256 + threadIdx.x;   // 256*512
    int e = idx & 511, s = idx >> 9;
    int j = e >> 1;
    float fr = __expf((float)(2 * j) * (-0.017988946f));   // -ln(10000)/512
    float ph = (float)s * fr;
    pe[idx] = (e & 1) ? cosf(ph) : sinf(ph);
}

__global__ __launch_bounds__(256) void add_pe_bf16(
    const float* __restrict__ in, const float* __restrict__ pe, u16* __restrict__ out)
{
    size_t idx = (size_t)blockIdx.x * 256 + threadIdx.x;   // 32768*512
    int e = (int)(idx & 511);
    int s = (int)(idx >> 16);
    out[idx] = f2bf(in[idx] + pe[(s << 9) | e]);
}

__global__ __launch_bounds__(128) void pool_sum(
    const float* __restrict__ t2, u16* __restrict__ pcat, int colofs)
{
    int b = blockIdx.x >> 2, ec = blockIdx.x & 3;
    int e = ec * 128 + threadIdx.x;
    float acc = 0.f;
    for (int s = 0; s < 256; ++s) acc += t2[(size_t)(s * 128 + b) * 512 + e];
    pcat[b * 1024 + colofs + e] = f2bf(acc * 0.0625f);     // / sqrt(256)
}

__global__ __launch_bounds__(64) void fc4_kernel(
    const u16* __restrict__ a, const float* __restrict__ w,
    const float* __restrict__ bias, float* __restrict__ out)
{
    int id = blockIdx.x * 64 + threadIdx.x;                // 384 = 128*3
    if (id >= 384) return;
    int b = id / 3, l = id % 3;
    float acc = bias[l];
    for (int k = 0; k < 512; ++k) acc += bf2f(a[b * 512 + k]) * w[k * 3 + l];
    out[id] = acc;
}

__global__ __launch_bounds__(64) void sentinel_kernel(float* __restrict__ out) {
    int i = blockIdx.x * 64 + threadIdx.x;
    if (i < 384) out[i] = -12345.0f;
}

// ===========================================================================
extern "C" void kernel_launch(void* const* d_in, const int* in_sizes, int n_in,
                              void* d_out, int out_size, void* d_ws, size_t ws_size,
                              hipStream_t stream) {
    (void)in_sizes; (void)n_in; (void)out_size;

    const float* x_1       = (const float*)d_in[0];
    const float* x_2       = (const float*)d_in[1];
    const float* enc_ln1_g = (const float*)d_in[2];
    const float* enc_ln1_b = (const float*)d_in[3];
    const float* enc_Wqkv  = (const float*)d_in[4];
    const float* enc_bqkv  = (const float*)d_in[5];
    const float* enc_Wo    = (const float*)d_in[6];
    const float* enc_bo    = (const float*)d_in[7];
    const float* enc_ln2_g = (const float*)d_in[8];
    const float* enc_ln2_b = (const float*)d_in[9];
    const float* enc_W1    = (const float*)d_in[10];
    const float* enc_b1    = (const float*)d_in[11];
    const float* enc_W2    = (const float*)d_in[12];
    const float* enc_b2    = (const float*)d_in[13];
    const float* isa_ln_g  = (const float*)d_in[14];
    const float* isa_ln_b  = (const float*)d_in[15];
    const float* isa_Wqkv  = (const float*)d_in[16];
    const float* isa_bqkv  = (const float*)d_in[17];
    const float* isa_Wo    = (const float*)d_in[18];
    const float* isa_bo    = (const float*)d_in[19];
    const float* iea_ln_g  = (const float*)d_in[20];
    const float* iea_ln_b  = (const float*)d_in[21];
    const float* iea_Wqkv  = (const float*)d_in[22];
    const float* iea_bqkv  = (const float*)d_in[23];
    const float* iea_Wo    = (const float*)d_in[24];
    const float* iea_bo    = (const float*)d_in[25];
    const float* iff_ln_g  = (const float*)d_in[26];
    const float* iff_ln_b  = (const float*)d_in[27];
    const float* int_W1    = (const float*)d_in[28];
    const float* int_b1    = (const float*)d_in[29];
    const float* int_W2    = (const float*)d_in[30];
    const float* int_b2    = (const float*)d_in[31];
    const float* fc1_w     = (const float*)d_in[32];
    const float* fc1_b     = (const float*)d_in[33];
    const float* fc2_w     = (const float*)d_in[34];
    const float* fc2_b     = (const float*)d_in[35];
    const float* fc3_w     = (const float*)d_in[36];
    const float* fc3_b     = (const float*)d_in[37];
    const float* fc4_w     = (const float*)d_in[38];
    const float* fc4_b     = (const float*)d_in[39];
    float* out = (float*)d_out;

    const size_t WS_NEED = 264318976;
    if (ws_size < WS_NEED) {                 // diagnostic: absmax ~12345 => ws too small
        sentinel_kernel<<<6, 64, 0, stream>>>(out);
        return;
    }

    char* ws = (char*)d_ws;
    // ---- persistent transposed weights (byte offsets) ----------------------
    u16* isaQKV = (u16*)(ws + 0);         // [3][1536][512]
    u16* isaWO  = (u16*)(ws + 4718592);   // [3][512][512]
    u16* ieaQKV = (u16*)(ws + 6291456);
    u16* ieaWO  = (u16*)(ws + 11010048);
    u16* intW1  = (u16*)(ws + 12582912);  // [3][2048][512]
    u16* intW2  = (u16*)(ws + 18874368);  // [3][512][2048]
    u16* fc1T   = (u16*)(ws + 25165824);  // [512][1024]
    u16* fc2T   = (u16*)(ws + 26214400);  // [512][512]
    u16* fc3T   = (u16*)(ws + 26738688);  // [512][1024]
    float* UD   = (float*)(ws + 27787264);
    float* enc_qkv_u = UD;                // [3][1536]
    float* enc_qkv_d = UD + 4608;
    float* enc_w1_u  = UD + 9216;         // [3][2048]
    float* enc_w1_d  = UD + 15360;
    float* isa_qkv_u = UD + 21504;
    float* isa_qkv_d = UD + 26112;
    float* iea_qkv_u = UD + 30720;
    float* iea_qkv_d = UD + 35328;
    float* int_w1_u  = UD + 39936;
    float* int_w1_d  = UD + 46080;
    float2* stats1 = (float2*)(ws + 27996160);   // [32768]
    float2* stats2 = (float2*)(ws + 28258304);
    float*  pe     = (float*)(ws + 28520448);    // [256,512]
    u16*    pcat   = (u16*)(ws + 29044736);      // [128,1024]
    u16*    fc3o   = (u16*)(ws + 29306880);      // [128,512]
    u16*    x1     = (u16*)(ws + 29437952);      // [32768,512] bf16 residual
    u16*    x2     = (u16*)(ws + 62992384);
    // EREG: during encoder holds enc transposed weights; afterwards e1/e2
    u16* encQKV = (u16*)(ws + 96546816);             // [3][1536][512]
    u16* encWO  = (u16*)(ws + 96546816 + 4718592);   // [3][512][512]
    u16* encW1  = (u16*)(ws + 96546816 + 6291456);   // [3][2048][512]
    u16* encW2  = (u16*)(ws + 96546816 + 12582912);  // [3][512][2048]
    u16* e1     = (u16*)(ws + 96546816);             // [32768,512]
    u16* e2     = (u16*)(ws + 96546816 + 33554432);
    // BIG scratch: 100 MB, phase-dependent
    u16*   qkv  = (u16*)(ws + 163655680);            // [32768,1536]
    u16*   B0   = (u16*)(ws + 163655680);            // [32768,512]
    u16*   B1   = (u16*)(ws + 163655680 + 33554432); // [32768,1024]
    u16*   fbuf = (u16*)(ws + 163655680);            // [32768,1024]
    u16*   dlt  = (u16*)(ws + 163655680 + 67108864); // [32768,512]
    float* accf = (float*)(ws + 163655680);          // [32768,512] fp32
    u16*   hcls = (u16*)(ws + 163655680 + 67108864); // [32768,512]

    // ---- weight prep -------------------------------------------------------
    auto TR = [&](const float* in, u16* o, const float* g, int K, int N, int L) {
        transpose_to_bf16<<<dim3(N / 32, K / 32, L), dim3(32, 8), 0, stream>>>(in, o, g, K, N);
    };
    TR(enc_Wqkv, encQKV, enc_ln1_g, 512, 1536, 3);
    TR(enc_Wo,   encWO,  nullptr,   512, 512,  3);
    TR(enc_W1,   encW1,  enc_ln2_g, 512, 2048, 3);
    TR(enc_W2,   encW2,  nullptr,   2048, 512, 3);
    TR(isa_Wqkv, isaQKV, isa_ln_g,  512, 1536, 3);
    TR(isa_Wo,   isaWO,  nullptr,   512, 512,  3);
    TR(iea_Wqkv, ieaQKV, iea_ln_g,  512, 1536, 3);
    TR(iea_Wo,   ieaWO,  nullptr,   512, 512,  3);
    TR(int_W1,   intW1,  iff_ln_g,  512, 2048, 3);
    TR(int_W2,   intW2,  nullptr,   2048, 512, 3);
    TR(fc1_w, fc1T, nullptr, 1024, 512, 1);
    TR(fc2_w, fc2T, nullptr, 512,  512, 1);
    TR(fc3_w, fc3T, nullptr, 1024, 512, 1);

    auto CS = [&](const float* W, const float* g, const float* b, const float* bias,
                  float* u, float* d, int K, int N, int L) {
        init_ud<<<N * L / 256, 256, 0, stream>>>(bias, u, d);
        colsum_part<<<dim3(N / 256, K / 32, L), 256, 0, stream>>>(W, g, b, u, d, K, N);
    };
    CS(enc_Wqkv, enc_ln1_g, enc_ln1_b, enc_bqkv, enc_qkv_u, enc_qkv_d, 512, 1536, 3);
    CS(enc_W1,   enc_ln2_g, enc_ln2_b, enc_b1,   enc_w1_u,  enc_w1_d,  512, 2048, 3);
    CS(isa_Wqkv, isa_ln_g,  isa_ln_b,  isa_bqkv, isa_qkv_u, isa_qkv_d, 512, 1536, 3);
    CS(iea_Wqkv, iea_ln_g,  iea_ln_b,  iea_bqkv, iea_qkv_u, iea_qkv_d, 512, 1536, 3);
    CS(int_W1,   iff_ln_g,  iff_ln_b,  int_b1,   int_w1_u,  int_w1_d,  512, 2048, 3);

    build_pe<<<512, 256, 0, stream>>>(pe);
    add_pe_bf16<<<65536, 256, 0, stream>>>(x_1, pe, x1);
    add_pe_bf16<<<65536, 256, 0, stream>>>(x_2, pe, x2);

    // ---- launch helpers ----------------------------------------------------
    auto G = [&](int epi, const u16* A, int lda, const u16* BT, int ldb,
                 const float* bias, const float* uu, const float2* stt,
                 void* C, int ldc, const float* resf, const u16* res16,
                 int M, int N, int K) {
        dim3 grid(N / 128, M / 128);
        switch (epi) {
        case 0: gemm_bt<0><<<grid, 256, 0, stream>>>(A, lda, BT, ldb, bias, uu, stt, C, ldc, resf, res16, M, N, K); break;
        case 1: gemm_bt<1><<<grid, 256, 0, stream>>>(A, lda, BT, ldb, bias, uu, stt, C, ldc, resf, res16, M, N, K); break;
        case 2: gemm_bt<2><<<grid, 256, 0, stream>>>(A, lda, BT, ldb, bias, uu, stt, C, ldc, resf, res16, M, N, K); break;
        case 3: gemm_bt<3><<<grid, 256, 0, stream>>>(A, lda, BT, ldb, bias, uu, stt, C, ldc, resf, res16, M, N, K); break;
        case 4: gemm_bt<4><<<grid, 256, 0, stream>>>(A, lda, BT, ldb, bias, uu, stt, C, ldc, resf, res16, M, N, K); break;
        case 5: gemm_bt<5><<<grid, 256, 0, stream>>>(A, lda, BT, ldb, bias, uu, stt, C, ldc, resf, res16, M, N, K); break;
        case 6: gemm_bt<6><<<grid, 256, 0, stream>>>(A, lda, BT, ldb, bias, uu, stt, C, ldc, resf, res16, M, N, K); break;
        case 8: gemm_bt<8><<<grid, 256, 0, stream>>>(A, lda, BT, ldb, bias, uu, stt, C, ldc, resf, res16, M, N, K); break;
        }
    };
    auto STATS = [&](const u16* x, float2* stt) {
        row_stats<<<8192, 256, 0, stream>>>(x, stt);
    };
    auto ATT = [&](const u16* Qp, int lq, const u16* Kp, const u16* Vp, int lkv,
                   u16* Op, int lo) {
        attn_kernel<<<dim3(1024), 512, 0, stream>>>(Qp, lq, Kp, Vp, lkv, Op, lo);
    };

    // self-attn + FFN block (encoder & interaction share the shape)
    auto self_block = [&](u16* x, u16* wqkvT, const float* qu, const float* qd,
                          u16* woT, const float* bo,
                          u16* w1T, const float* w1u, const float* w1d,
                          u16* w2T, const float* b2, bool do_ffn) {
        STATS(x, stats1);
        G(5, x, 512, wqkvT, 512, qd, qu, stats1, qkv, 1536, nullptr, nullptr, 32768, 1536, 512);
        ATT(qkv, 1536, qkv + 512, qkv + 1024, 1536, qkv, 1536);
        G(2, qkv, 1536, woT, 512, bo, nullptr, nullptr, x, 512, nullptr, nullptr, 32768, 512, 512);
        if (do_ffn) {
            STATS(x, stats1);
            G(6, x, 512, w1T, 512, w1d, w1u, stats1, fbuf, 1024, nullptr, nullptr, 32768, 1024, 512);
            G(0, fbuf, 1024, w2T, 2048, b2, nullptr, nullptr, dlt, 512, nullptr, nullptr, 32768, 512, 1024);
            G(6, x, 512, w1T + 1024 * 512, 512, w1d + 1024, w1u + 1024, stats1, fbuf, 1024, nullptr, nullptr, 32768, 1024, 512);
            G(8, fbuf, 1024, w2T + 1024, 2048, nullptr, nullptr, nullptr, x, 512, nullptr, dlt, 32768, 512, 1024);
        }
    };

    // ---- Siamese encoder ---------------------------------------------------
    for (int i = 0; i < 3; ++i)
        for (int st = 0; st < 2; ++st)
            self_block(st ? x2 : x1,
                       encQKV + (size_t)i * 786432, enc_qkv_u + i * 1536, enc_qkv_d + i * 1536,
                       encWO + (size_t)i * 262144, enc_bo + i * 512,
                       encW1 + (size_t)i * 1048576, enc_w1_u + i * 2048, enc_w1_d + i * 2048,
                       encW2 + (size_t)i * 1048576, enc_b2 + i * 512, true);

    // snapshots (enc weights in EREG are dead now)
    hipMemcpyAsync(e1, x1, 33554432, hipMemcpyDeviceToDevice, stream);
    hipMemcpyAsync(e2, x2, 33554432, hipMemcpyDeviceToDevice, stream);

    // ---- interaction stack -------------------------------------------------
    for (int i = 0; i < 3; ++i) {
        // self-attn (isa), no FFN inside
        for (int st = 0; st < 2; ++st)
            self_block(st ? x2 : x1,
                       isaQKV + (size_t)i * 786432, isa_qkv_u + i * 1536, isa_qkv_d + i * 1536,
                       isaWO + (size_t)i * 262144, isa_bo + i * 512,
                       nullptr, nullptr, nullptr, nullptr, nullptr, false);
        // cross-attn (iea): h1,h2 from pre-update x1,x2
        u16* qT  = ieaQKV + (size_t)i * 786432;
        u16* kvT = qT + 512 * 512;
        const float* qu = iea_qkv_u + i * 1536;
        const float* qd = iea_qkv_d + i * 1536;
        STATS(x2, stats2);
        G(5, x2, 512, kvT, 512, qd + 512, qu + 512, stats2, B1, 1024, nullptr, nullptr, 32768, 1024, 512); // kv2
        STATS(x1, stats1);
        G(5, x1, 512, qT, 512, qd, qu, stats1, B0, 512, nullptr, nullptr, 32768, 512, 512);               // q1
        ATT(B0, 512, B1, B1 + 512, 1024, B0, 512);                                                        // ctx1
        G(5, x1, 512, kvT, 512, qd + 512, qu + 512, stats1, B1, 1024, nullptr, nullptr, 32768, 1024, 512); // kv1 (x1 old)
        G(2, B0, 512, ieaWO + (size_t)i * 262144, 512, iea_bo + i * 512, nullptr, nullptr,
          x1, 512, nullptr, nullptr, 32768, 512, 512);                                                    // x1 += y1
        G(5, x2, 512, qT, 512, qd, qu, stats2, B0, 512, nullptr, nullptr, 32768, 512, 512);               // q2 (x2 old)
        ATT(B0, 512, B1, B1 + 512, 1024, B0, 512);                                                        // ctx2
        G(2, B0, 512, ieaWO + (size_t)i * 262144, 512, iea_bo + i * 512, nullptr, nullptr,
          x2, 512, nullptr, nullptr, 32768, 512, 512);                                                    // x2 += y2
        // FFN (int/iff)
        for (int st = 0; st < 2; ++st) {
            u16* x = st ? x2 : x1;
            STATS(x, stats1);
            u16* w1T = intW1 + (size_t)i * 1048576;
            u16* w2T = intW2 + (size_t)i * 1048576;
            const float* w1u = int_w1_u + i * 2048;
            const float* w1d = int_w1_d + i * 2048;
            G(6, x, 512, w1T, 512, w1d, w1u, stats1, fbuf, 1024, nullptr, nullptr, 32768, 1024, 512);
            G(0, fbuf, 1024, w2T, 2048, int_b2 + i * 512, nullptr, nullptr, dlt, 512, nullptr, nullptr, 32768, 512, 1024);
            G(6, x, 512, w1T + 1024 * 512, 512, w1d + 1024, w1u + 1024, stats1, fbuf, 1024, nullptr, nullptr, 32768, 1024, 512);
            G(8, fbuf, 1024, w2T + 1024, 2048, nullptr, nullptr, nullptr, x, 512, nullptr, dlt, 32768, 512, 1024);
        }
    }

    // ---- classifier --------------------------------------------------------
    for (int st = 0; st < 2; ++st) {
        const u16* e = st ? e2 : e1;
        const u16* x = st ? x2 : x1;
        G(3, e, 512, fc1T, 1024, nullptr, nullptr, nullptr, accf, 512, nullptr, nullptr, 32768, 512, 512);   // e-part, fp32
        G(4, x, 512, fc1T + 512, 1024, fc1_b, nullptr, nullptr, hcls, 512, accf, nullptr, 32768, 512, 512);  // relu(e+i+b)
        G(3, hcls, 512, fc2T, 512, fc2_b, nullptr, nullptr, accf, 512, nullptr, nullptr, 32768, 512, 512);   // fp32 t2
        pool_sum<<<512, 128, 0, stream>>>(accf, pcat, st * 512);
    }
    G(1, pcat, 1024, fc3T, 1024, fc3_b, nullptr, nullptr, fc3o, 512, nullptr, nullptr, 128, 512, 1024);
    fc4_kernel<<<6, 64, 0, stream>>>(fc3o, fc4_w, fc4_b, out);
}